// Round 1
// baseline (309.181 us; speedup 1.0000x reference)
//
#include <hip/hip_runtime.h>

#define NNODES 50000
#define NEDGES 800000
#define FDIM 128
#define HDIM 128
#define CDIM 16

// ---------------- CSR build ----------------

__global__ void k_zero_i32(int* __restrict__ p, int n) {
  int i = blockIdx.x * blockDim.x + threadIdx.x;
  if (i < n) p[i] = 0;
}

__global__ void k_count(const int* __restrict__ dst, int* __restrict__ deg, int E) {
  int e = blockIdx.x * blockDim.x + threadIdx.x;
  if (e < E) atomicAdd(&deg[dst[e]], 1);
}

// per-256-chunk exclusive scan; chunk totals into part[]
__global__ void k_scan1(const int* __restrict__ deg, int* __restrict__ offs,
                        int* __restrict__ part, int n) {
  __shared__ int s[256];
  int tid = threadIdx.x;
  int i = blockIdx.x * 256 + tid;
  int v = (i < n) ? deg[i] : 0;
  s[tid] = v;
  for (int off = 1; off < 256; off <<= 1) {
    __syncthreads();
    int t = (tid >= off) ? s[tid - off] : 0;
    __syncthreads();
    s[tid] += t;
  }
  if (i < n) offs[i] = s[tid] - v;            // exclusive within chunk
  if (tid == 255) part[blockIdx.x] = s[255];  // chunk total
}

// exclusive scan of chunk totals (nb <= 256)
__global__ void k_scan2(int* __restrict__ part, int nb) {
  __shared__ int s[256];
  int tid = threadIdx.x;
  int v = (tid < nb) ? part[tid] : 0;
  s[tid] = v;
  for (int off = 1; off < 256; off <<= 1) {
    __syncthreads();
    int t = (tid >= off) ? s[tid - off] : 0;
    __syncthreads();
    s[tid] += t;
  }
  if (tid < nb) part[tid] = s[tid] - v;
}

__global__ void k_scan3(int* __restrict__ offs, const int* __restrict__ part,
                        int* __restrict__ curs, int n) {
  int i = blockIdx.x * blockDim.x + threadIdx.x;
  if (i < n) {
    int o = offs[i] + part[i >> 8];
    offs[i] = o;
    curs[i] = o;
  }
}

__global__ void k_fill(const int* __restrict__ src, const int* __restrict__ dst,
                       int* __restrict__ curs, int* __restrict__ ssrc, int E) {
  int e = blockIdx.x * blockDim.x + threadIdx.x;
  if (e < E) {
    int pos = atomicAdd(&curs[dst[e]], 1);
    ssrc[pos] = src[e];
  }
}

// ---------------- layer 1: mean-aggregate x (pull form) ----------------
// one block (128 threads) per node; thread = channel
__global__ void k_spmm1(const float* __restrict__ x, const int* __restrict__ offs,
                        const int* __restrict__ deg, const int* __restrict__ ssrc,
                        float* __restrict__ agg) {
  int n = blockIdx.x;
  int tid = threadIdx.x;  // 0..127
  int start = offs[n];
  int d = deg[n];
  float a0 = 0.f, a1 = 0.f;
  int j = 0;
  for (; j + 1 < d; j += 2) {
    int s0 = ssrc[start + j];
    int s1 = ssrc[start + j + 1];
    a0 += x[s0 * FDIM + tid];
    a1 += x[s1 * FDIM + tid];
  }
  if (j < d) a0 += x[ssrc[start + j] * FDIM + tid];
  float inv = 1.0f / (float)(d > 0 ? d : 1);
  agg[n * FDIM + tid] = (a0 + a1) * inv;
}

// ---------------- fused dense: h = relu(agg @ W1 + b1) * mask ----------------
// block = 256 threads computes 64 nodes x 128 cols; thread tile 8n x 4c
__global__ __launch_bounds__(256) void k_gemm_fused(
    const float* __restrict__ agg, const float* __restrict__ W1,
    const float* __restrict__ b1, const float* __restrict__ mask,
    float* __restrict__ h) {
  __shared__ float As[128][68];   // [k][n], padded stride 68 (16B-aligned rows)
  __shared__ float Bs[16 * 128];  // W1 k-chunk [16][128]
  int tid = threadIdx.x;
  int nb = blockIdx.x * 64;

  // stage agg tile transposed: As[k][n]
  int r = tid >> 2;   // 0..63 node
  int c4 = tid & 3;   // 0..3
  bool rv = (nb + r) < NNODES;
  #pragma unroll
  for (int i = 0; i < 8; ++i) {
    int k0 = c4 * 4 + i * 16;
    float4 v = rv ? *reinterpret_cast<const float4*>(&agg[(size_t)(nb + r) * 128 + k0])
                  : make_float4(0.f, 0.f, 0.f, 0.f);
    As[k0 + 0][r] = v.x; As[k0 + 1][r] = v.y; As[k0 + 2][r] = v.z; As[k0 + 3][r] = v.w;
  }

  int tn = tid & 7;   // nodes 8*tn .. 8*tn+7
  int tc = tid >> 3;  // cols  4*tc .. 4*tc+3
  float acc[8][4];
  #pragma unroll
  for (int i = 0; i < 8; ++i)
    #pragma unroll
    for (int j = 0; j < 4; ++j) acc[i][j] = 0.f;

  for (int kc = 0; kc < 8; ++kc) {
    __syncthreads();  // As ready (first iter) / previous compute done
    {
      float4 v0 = *reinterpret_cast<const float4*>(&W1[kc * 16 * 128 + tid * 4]);
      float4 v1 = *reinterpret_cast<const float4*>(&W1[kc * 16 * 128 + 1024 + tid * 4]);
      *reinterpret_cast<float4*>(&Bs[tid * 4]) = v0;
      *reinterpret_cast<float4*>(&Bs[1024 + tid * 4]) = v1;
    }
    __syncthreads();
    #pragma unroll
    for (int k = 0; k < 16; ++k) {
      const float4* ap = reinterpret_cast<const float4*>(&As[kc * 16 + k][8 * tn]);
      float4 a0 = ap[0], a1 = ap[1];
      float4 b = *reinterpret_cast<const float4*>(&Bs[k * 128 + 4 * tc]);
      float av[8] = {a0.x, a0.y, a0.z, a0.w, a1.x, a1.y, a1.z, a1.w};
      float bv[4] = {b.x, b.y, b.z, b.w};
      #pragma unroll
      for (int i = 0; i < 8; ++i)
        #pragma unroll
        for (int j = 0; j < 4; ++j) acc[i][j] += av[i] * bv[j];
    }
  }

  // epilogue: +b1, relu, *mask -> h
  float4 b1v = *reinterpret_cast<const float4*>(&b1[4 * tc]);
  float bb[4] = {b1v.x, b1v.y, b1v.z, b1v.w};
  #pragma unroll
  for (int i = 0; i < 8; ++i) {
    int n = nb + 8 * tn + i;
    if (n < NNODES) {
      float4 m = *reinterpret_cast<const float4*>(&mask[(size_t)n * 128 + 4 * tc]);
      float mv[4] = {m.x, m.y, m.z, m.w};
      float vals[4];
      #pragma unroll
      for (int j = 0; j < 4; ++j) {
        float v = acc[i][j] + bb[j];
        v = v > 0.f ? v : 0.f;
        vals[j] = v * mv[j];
      }
      float4 o; o.x = vals[0]; o.y = vals[1]; o.z = vals[2]; o.w = vals[3];
      *reinterpret_cast<float4*>(&h[(size_t)n * 128 + 4 * tc]) = o;
    }
  }
}

// ---------------- z = h @ W2 (N x 128 @ 128 x 16) ----------------
__global__ __launch_bounds__(256) void k_gemm2(
    const float* __restrict__ h, const float* __restrict__ W2,
    float* __restrict__ z) {
  __shared__ float Hs[128][68];
  __shared__ float W2s[128 * 16];
  int tid = threadIdx.x;
  int nb = blockIdx.x * 64;
  int r = tid >> 2, c4 = tid & 3;
  bool rv = (nb + r) < NNODES;
  #pragma unroll
  for (int i = 0; i < 8; ++i) {
    int k0 = c4 * 4 + i * 16;
    float4 v = rv ? *reinterpret_cast<const float4*>(&h[(size_t)(nb + r) * 128 + k0])
                  : make_float4(0.f, 0.f, 0.f, 0.f);
    Hs[k0 + 0][r] = v.x; Hs[k0 + 1][r] = v.y; Hs[k0 + 2][r] = v.z; Hs[k0 + 3][r] = v.w;
  }
  {
    float4 v0 = *reinterpret_cast<const float4*>(&W2[tid * 4]);
    float4 v1 = *reinterpret_cast<const float4*>(&W2[1024 + tid * 4]);
    *reinterpret_cast<float4*>(&W2s[tid * 4]) = v0;
    *reinterpret_cast<float4*>(&W2s[1024 + tid * 4]) = v1;
  }
  __syncthreads();
  int tn2 = tid & 31;  // node pair 2*tn2, 2*tn2+1
  int tc2 = tid >> 5;  // col pair 2*tc2, 2*tc2+1
  float acc00 = 0, acc01 = 0, acc10 = 0, acc11 = 0;
  #pragma unroll 16
  for (int k = 0; k < 128; ++k) {
    float2 a = *reinterpret_cast<const float2*>(&Hs[k][2 * tn2]);
    float2 b = *reinterpret_cast<const float2*>(&W2s[k * 16 + 2 * tc2]);
    acc00 += a.x * b.x; acc01 += a.x * b.y;
    acc10 += a.y * b.x; acc11 += a.y * b.y;
  }
  int n0 = nb + 2 * tn2;
  if (n0 < NNODES) {
    z[n0 * 16 + 2 * tc2] = acc00;
    z[n0 * 16 + 2 * tc2 + 1] = acc01;
  }
  if (n0 + 1 < NNODES) {
    z[(n0 + 1) * 16 + 2 * tc2] = acc10;
    z[(n0 + 1) * 16 + 2 * tc2 + 1] = acc11;
  }
}

// ---------------- layer 2 aggregate + bias: out = mean(z) + b2 ----------------
// block = 128 threads = 8 nodes x 16 channels
__global__ void k_spmm2(const float* __restrict__ z, const int* __restrict__ offs,
                        const int* __restrict__ deg, const int* __restrict__ ssrc,
                        const float* __restrict__ b2, float* __restrict__ out) {
  int tid = threadIdx.x;
  int nl = tid >> 4, c = tid & 15;
  int n = blockIdx.x * 8 + nl;
  if (n >= NNODES) return;
  int start = offs[n], d = deg[n];
  float a0 = 0.f, a1 = 0.f;
  int j = 0;
  for (; j + 1 < d; j += 2) {
    int s0 = ssrc[start + j], s1 = ssrc[start + j + 1];
    a0 += z[s0 * 16 + c];
    a1 += z[s1 * 16 + c];
  }
  if (j < d) a0 += z[ssrc[start + j] * 16 + c];
  out[n * 16 + c] = (a0 + a1) / (float)(d > 0 ? d : 1) + b2[c];
}

// ---------------- launch ----------------

extern "C" void kernel_launch(void* const* d_in, const int* in_sizes, int n_in,
                              void* d_out, int out_size, void* d_ws, size_t ws_size,
                              hipStream_t stream) {
  const float* x    = (const float*)d_in[0];
  const int*   ei   = (const int*)d_in[1];
  const float* W1   = (const float*)d_in[2];
  const float* b1   = (const float*)d_in[3];
  const float* W2   = (const float*)d_in[4];
  const float* b2   = (const float*)d_in[5];
  const float* mask = (const float*)d_in[6];
  float* out = (float*)d_out;

  const int* src = ei;            // edge_index[0]
  const int* dst = ei + NEDGES;   // edge_index[1]

  char* ws = (char*)d_ws;
  size_t o = 0;
  auto alloc = [&](size_t bytes) -> void* {
    void* p = ws + o;
    o += (bytes + 255) & ~(size_t)255;
    return p;
  };
  float* agg  = (float*)alloc((size_t)NNODES * 128 * 4);
  float* h    = (float*)alloc((size_t)NNODES * 128 * 4);
  int*   deg  = (int*)alloc((size_t)NNODES * 4);
  int*   offs = (int*)alloc((size_t)NNODES * 4);
  int*   curs = (int*)alloc((size_t)NNODES * 4);
  int*   ssrc = (int*)alloc((size_t)NEDGES * 4);
  int*   part = (int*)alloc(256 * 4);
  float* z    = agg;  // overlay: agg is dead after k_gemm_fused

  int NB = (NNODES + 255) / 256;

  k_zero_i32<<<NB, 256, 0, stream>>>(deg, NNODES);
  k_count<<<(NEDGES + 255) / 256, 256, 0, stream>>>(dst, deg, NEDGES);
  k_scan1<<<NB, 256, 0, stream>>>(deg, offs, part, NNODES);
  k_scan2<<<1, 256, 0, stream>>>(part, NB);
  k_scan3<<<NB, 256, 0, stream>>>(offs, part, curs, NNODES);
  k_fill<<<(NEDGES + 255) / 256, 256, 0, stream>>>(src, dst, curs, ssrc, NEDGES);
  k_spmm1<<<NNODES, 128, 0, stream>>>(x, offs, deg, ssrc, agg);
  k_gemm_fused<<<(NNODES + 63) / 64, 256, 0, stream>>>(agg, W1, b1, mask, h);
  k_gemm2<<<(NNODES + 63) / 64, 256, 0, stream>>>(h, W2, z);
  k_spmm2<<<(NNODES + 7) / 8, 128, 0, stream>>>(z, offs, deg, ssrc, b2, out);
}

// Round 3
// 294.171 us; speedup vs baseline: 1.0510x; 1.0510x over previous
//
#include <hip/hip_runtime.h>

#define NNODES 50000
#define NEDGES 800000
#define FDIM 128
#define HDIM 128
#define CDIM 16

// ---------------- CSR build ----------------

__global__ void k_zero_i32(int* __restrict__ p, int n) {
  int i = blockIdx.x * blockDim.x + threadIdx.x;
  if (i < n) p[i] = 0;
}

__global__ void k_count(const int* __restrict__ dst, int* __restrict__ deg, int E) {
  int e = blockIdx.x * blockDim.x + threadIdx.x;
  if (e < E) atomicAdd(&deg[dst[e]], 1);
}

// per-256-chunk exclusive scan; chunk totals into part[]
__global__ void k_scan1(const int* __restrict__ deg, int* __restrict__ offs,
                        int* __restrict__ part, int n) {
  __shared__ int s[256];
  int tid = threadIdx.x;
  int i = blockIdx.x * 256 + tid;
  int v = (i < n) ? deg[i] : 0;
  s[tid] = v;
  for (int off = 1; off < 256; off <<= 1) {
    __syncthreads();
    int t = (tid >= off) ? s[tid - off] : 0;
    __syncthreads();
    s[tid] += t;
  }
  if (i < n) offs[i] = s[tid] - v;            // exclusive within chunk
  if (tid == 255) part[blockIdx.x] = s[255];  // chunk total
}

// exclusive scan of chunk totals (nb <= 256)
__global__ void k_scan2(int* __restrict__ part, int nb) {
  __shared__ int s[256];
  int tid = threadIdx.x;
  int v = (tid < nb) ? part[tid] : 0;
  s[tid] = v;
  for (int off = 1; off < 256; off <<= 1) {
    __syncthreads();
    int t = (tid >= off) ? s[tid - off] : 0;
    __syncthreads();
    s[tid] += t;
  }
  if (tid < nb) part[tid] = s[tid] - v;
}

__global__ void k_scan3(int* __restrict__ offs, const int* __restrict__ part,
                        int* __restrict__ curs, int n) {
  int i = blockIdx.x * blockDim.x + threadIdx.x;
  if (i < n) {
    int o = offs[i] + part[i >> 8];
    offs[i] = o;
    curs[i] = o;
  }
}

__global__ void k_fill(const int* __restrict__ src, const int* __restrict__ dst,
                       int* __restrict__ curs, int* __restrict__ ssrc, int E) {
  int e = blockIdx.x * blockDim.x + threadIdx.x;
  if (e < E) {
    int pos = atomicAdd(&curs[dst[e]], 1);
    ssrc[pos] = src[e];
  }
}

// ---------------- cast x -> bf16 (manual RNE) ----------------
__device__ __forceinline__ ushort f32_to_bf16_rne(float f) {
  unsigned u = __float_as_uint(f);
  unsigned rounded = u + 0x7fffu + ((u >> 16) & 1u);
  return (ushort)(rounded >> 16);
}

// n4 threads, 4 floats each (float4 read, 4x bf16 = 8B write)
__global__ void k_cast_bf16(const float* __restrict__ x, ushort* __restrict__ xh, int n4) {
  int i = blockIdx.x * blockDim.x + threadIdx.x;
  if (i < n4) {
    float4 v = *reinterpret_cast<const float4*>(&x[i * 4]);
    ushort4 o;
    o.x = f32_to_bf16_rne(v.x);
    o.y = f32_to_bf16_rne(v.y);
    o.z = f32_to_bf16_rne(v.z);
    o.w = f32_to_bf16_rne(v.w);
    *reinterpret_cast<ushort4*>(&xh[i * 4]) = o;
  }
}

// ---------------- layer 1: mean-aggregate bf16 x (pull form) ----------------
// one wave (64 lanes) per node; lane owns channels {2*lane, 2*lane+1}
// each edge: 64 lanes x ushort2 = one 256B row load
__global__ __launch_bounds__(256) void k_spmm1(
    const ushort* __restrict__ xh, const int* __restrict__ offs,
    const int* __restrict__ deg, const int* __restrict__ ssrc,
    float* __restrict__ agg) {
  int n = blockIdx.x * 4 + (threadIdx.x >> 6);
  if (n >= NNODES) return;
  int lane = threadIdx.x & 63;
  int start = offs[n];
  int d = deg[n];
  float2 acc0 = {0.f, 0.f}, acc1 = {0.f, 0.f};
  float2 acc2 = {0.f, 0.f}, acc3 = {0.f, 0.f};
  int j = 0;
  for (; j + 3 < d; j += 4) {
    int s0 = ssrc[start + j + 0];
    int s1 = ssrc[start + j + 1];
    int s2 = ssrc[start + j + 2];
    int s3 = ssrc[start + j + 3];
    unsigned u0 = *reinterpret_cast<const unsigned*>(&xh[s0 * FDIM + 2 * lane]);
    unsigned u1 = *reinterpret_cast<const unsigned*>(&xh[s1 * FDIM + 2 * lane]);
    unsigned u2 = *reinterpret_cast<const unsigned*>(&xh[s2 * FDIM + 2 * lane]);
    unsigned u3 = *reinterpret_cast<const unsigned*>(&xh[s3 * FDIM + 2 * lane]);
    acc0.x += __uint_as_float(u0 << 16);
    acc0.y += __uint_as_float(u0 & 0xffff0000u);
    acc1.x += __uint_as_float(u1 << 16);
    acc1.y += __uint_as_float(u1 & 0xffff0000u);
    acc2.x += __uint_as_float(u2 << 16);
    acc2.y += __uint_as_float(u2 & 0xffff0000u);
    acc3.x += __uint_as_float(u3 << 16);
    acc3.y += __uint_as_float(u3 & 0xffff0000u);
  }
  for (; j < d; ++j) {
    int s0 = ssrc[start + j];
    unsigned u0 = *reinterpret_cast<const unsigned*>(&xh[s0 * FDIM + 2 * lane]);
    acc0.x += __uint_as_float(u0 << 16);
    acc0.y += __uint_as_float(u0 & 0xffff0000u);
  }
  float inv = 1.0f / (float)(d > 0 ? d : 1);
  float2 r;
  r.x = (acc0.x + acc1.x + acc2.x + acc3.x) * inv;
  r.y = (acc0.y + acc1.y + acc2.y + acc3.y) * inv;
  *reinterpret_cast<float2*>(&agg[(size_t)n * FDIM + 2 * lane]) = r;
}

// ---------------- fused dense: h = relu(agg @ W1 + b1) * mask ----------------
// block = 256 threads computes 64 nodes x 128 cols; thread tile 8n x 4c
__global__ __launch_bounds__(256) void k_gemm_fused(
    const float* __restrict__ agg, const float* __restrict__ W1,
    const float* __restrict__ b1, const float* __restrict__ mask,
    float* __restrict__ h) {
  __shared__ float As[128][68];   // [k][n], padded stride 68 (16B-aligned rows)
  __shared__ float Bs[16 * 128];  // W1 k-chunk [16][128]
  int tid = threadIdx.x;
  int nb = blockIdx.x * 64;

  // stage agg tile transposed: As[k][n]
  int r = tid >> 2;   // 0..63 node
  int c4 = tid & 3;   // 0..3
  bool rv = (nb + r) < NNODES;
  #pragma unroll
  for (int i = 0; i < 8; ++i) {
    int k0 = c4 * 4 + i * 16;
    float4 v = rv ? *reinterpret_cast<const float4*>(&agg[(size_t)(nb + r) * 128 + k0])
                  : make_float4(0.f, 0.f, 0.f, 0.f);
    As[k0 + 0][r] = v.x; As[k0 + 1][r] = v.y; As[k0 + 2][r] = v.z; As[k0 + 3][r] = v.w;
  }

  int tn = tid & 7;   // nodes 8*tn .. 8*tn+7
  int tc = tid >> 3;  // cols  4*tc .. 4*tc+3
  float acc[8][4];
  #pragma unroll
  for (int i = 0; i < 8; ++i)
    #pragma unroll
    for (int j = 0; j < 4; ++j) acc[i][j] = 0.f;

  for (int kc = 0; kc < 8; ++kc) {
    __syncthreads();  // As ready (first iter) / previous compute done
    {
      float4 v0 = *reinterpret_cast<const float4*>(&W1[kc * 16 * 128 + tid * 4]);
      float4 v1 = *reinterpret_cast<const float4*>(&W1[kc * 16 * 128 + 1024 + tid * 4]);
      *reinterpret_cast<float4*>(&Bs[tid * 4]) = v0;
      *reinterpret_cast<float4*>(&Bs[1024 + tid * 4]) = v1;
    }
    __syncthreads();
    #pragma unroll
    for (int k = 0; k < 16; ++k) {
      const float4* ap = reinterpret_cast<const float4*>(&As[kc * 16 + k][8 * tn]);
      float4 a0 = ap[0], a1 = ap[1];
      float4 b = *reinterpret_cast<const float4*>(&Bs[k * 128 + 4 * tc]);
      float av[8] = {a0.x, a0.y, a0.z, a0.w, a1.x, a1.y, a1.z, a1.w};
      float bv[4] = {b.x, b.y, b.z, b.w};
      #pragma unroll
      for (int i = 0; i < 8; ++i)
        #pragma unroll
        for (int j = 0; j < 4; ++j) acc[i][j] += av[i] * bv[j];
    }
  }

  // epilogue: +b1, relu, *mask -> h
  float4 b1v = *reinterpret_cast<const float4*>(&b1[4 * tc]);
  float bb[4] = {b1v.x, b1v.y, b1v.z, b1v.w};
  #pragma unroll
  for (int i = 0; i < 8; ++i) {
    int n = nb + 8 * tn + i;
    if (n < NNODES) {
      float4 m = *reinterpret_cast<const float4*>(&mask[(size_t)n * 128 + 4 * tc]);
      float mv[4] = {m.x, m.y, m.z, m.w};
      float vals[4];
      #pragma unroll
      for (int j = 0; j < 4; ++j) {
        float v = acc[i][j] + bb[j];
        v = v > 0.f ? v : 0.f;
        vals[j] = v * mv[j];
      }
      float4 o; o.x = vals[0]; o.y = vals[1]; o.z = vals[2]; o.w = vals[3];
      *reinterpret_cast<float4*>(&h[(size_t)n * 128 + 4 * tc]) = o;
    }
  }
}

// ---------------- z = h @ W2 (N x 128 @ 128 x 16) ----------------
__global__ __launch_bounds__(256) void k_gemm2(
    const float* __restrict__ h, const float* __restrict__ W2,
    float* __restrict__ z) {
  __shared__ float Hs[128][68];
  __shared__ float W2s[128 * 16];
  int tid = threadIdx.x;
  int nb = blockIdx.x * 64;
  int r = tid >> 2, c4 = tid & 3;
  bool rv = (nb + r) < NNODES;
  #pragma unroll
  for (int i = 0; i < 8; ++i) {
    int k0 = c4 * 4 + i * 16;
    float4 v = rv ? *reinterpret_cast<const float4*>(&h[(size_t)(nb + r) * 128 + k0])
                  : make_float4(0.f, 0.f, 0.f, 0.f);
    Hs[k0 + 0][r] = v.x; Hs[k0 + 1][r] = v.y; Hs[k0 + 2][r] = v.z; Hs[k0 + 3][r] = v.w;
  }
  {
    float4 v0 = *reinterpret_cast<const float4*>(&W2[tid * 4]);
    float4 v1 = *reinterpret_cast<const float4*>(&W2[1024 + tid * 4]);
    *reinterpret_cast<float4*>(&W2s[tid * 4]) = v0;
    *reinterpret_cast<float4*>(&W2s[1024 + tid * 4]) = v1;
  }
  __syncthreads();
  int tn2 = tid & 31;  // node pair 2*tn2, 2*tn2+1
  int tc2 = tid >> 5;  // col pair 2*tc2, 2*tc2+1
  float acc00 = 0, acc01 = 0, acc10 = 0, acc11 = 0;
  #pragma unroll 16
  for (int k = 0; k < 128; ++k) {
    float2 a = *reinterpret_cast<const float2*>(&Hs[k][2 * tn2]);
    float2 b = *reinterpret_cast<const float2*>(&W2s[k * 16 + 2 * tc2]);
    acc00 += a.x * b.x; acc01 += a.x * b.y;
    acc10 += a.y * b.x; acc11 += a.y * b.y;
  }
  int n0 = nb + 2 * tn2;
  if (n0 < NNODES) {
    z[n0 * 16 + 2 * tc2] = acc00;
    z[n0 * 16 + 2 * tc2 + 1] = acc01;
  }
  if (n0 + 1 < NNODES) {
    z[(n0 + 1) * 16 + 2 * tc2] = acc10;
    z[(n0 + 1) * 16 + 2 * tc2 + 1] = acc11;
  }
}

// ---------------- layer 2 aggregate + bias: out = mean(z) + b2 ----------------
// block = 128 threads = 8 nodes x 16 channels
__global__ void k_spmm2(const float* __restrict__ z, const int* __restrict__ offs,
                        const int* __restrict__ deg, const int* __restrict__ ssrc,
                        const float* __restrict__ b2, float* __restrict__ out) {
  int tid = threadIdx.x;
  int nl = tid >> 4, c = tid & 15;
  int n = blockIdx.x * 8 + nl;
  if (n >= NNODES) return;
  int start = offs[n], d = deg[n];
  float a0 = 0.f, a1 = 0.f, a2 = 0.f, a3 = 0.f;
  int j = 0;
  for (; j + 3 < d; j += 4) {
    int s0 = ssrc[start + j + 0], s1 = ssrc[start + j + 1];
    int s2 = ssrc[start + j + 2], s3 = ssrc[start + j + 3];
    a0 += z[s0 * 16 + c];
    a1 += z[s1 * 16 + c];
    a2 += z[s2 * 16 + c];
    a3 += z[s3 * 16 + c];
  }
  for (; j < d; ++j) a0 += z[ssrc[start + j] * 16 + c];
  out[n * 16 + c] = (a0 + a1 + a2 + a3) / (float)(d > 0 ? d : 1) + b2[c];
}

// ---------------- launch ----------------

extern "C" void kernel_launch(void* const* d_in, const int* in_sizes, int n_in,
                              void* d_out, int out_size, void* d_ws, size_t ws_size,
                              hipStream_t stream) {
  const float* x    = (const float*)d_in[0];
  const int*   ei   = (const int*)d_in[1];
  const float* W1   = (const float*)d_in[2];
  const float* b1   = (const float*)d_in[3];
  const float* W2   = (const float*)d_in[4];
  const float* b2   = (const float*)d_in[5];
  const float* mask = (const float*)d_in[6];
  float* out = (float*)d_out;

  const int* src = ei;            // edge_index[0]
  const int* dst = ei + NEDGES;   // edge_index[1]

  char* ws = (char*)d_ws;
  size_t o = 0;
  auto alloc = [&](size_t bytes) -> void* {
    void* p = ws + o;
    o += (bytes + 255) & ~(size_t)255;
    return p;
  };
  float*  agg  = (float*)alloc((size_t)NNODES * 128 * 4);
  float*  h    = (float*)alloc((size_t)NNODES * 128 * 4);
  ushort* xh   = (ushort*)alloc((size_t)NNODES * 128 * 2);
  int*    deg  = (int*)alloc((size_t)NNODES * 4);
  int*    offs = (int*)alloc((size_t)NNODES * 4);
  int*    curs = (int*)alloc((size_t)NNODES * 4);
  int*    ssrc = (int*)alloc((size_t)NEDGES * 4);
  int*    part = (int*)alloc(256 * 4);
  float*  z    = agg;  // overlay: agg is dead after k_gemm_fused

  int NB = (NNODES + 255) / 256;

  k_zero_i32<<<NB, 256, 0, stream>>>(deg, NNODES);
  k_cast_bf16<<<(NNODES * 128 / 4 + 255) / 256, 256, 0, stream>>>(x, xh, NNODES * 128 / 4);
  k_count<<<(NEDGES + 255) / 256, 256, 0, stream>>>(dst, deg, NEDGES);
  k_scan1<<<NB, 256, 0, stream>>>(deg, offs, part, NNODES);
  k_scan2<<<1, 256, 0, stream>>>(part, NB);
  k_scan3<<<NB, 256, 0, stream>>>(offs, part, curs, NNODES);
  k_fill<<<(NEDGES + 255) / 256, 256, 0, stream>>>(src, dst, curs, ssrc, NEDGES);
  k_spmm1<<<(NNODES + 3) / 4, 256, 0, stream>>>(xh, offs, deg, ssrc, agg);
  k_gemm_fused<<<(NNODES + 63) / 64, 256, 0, stream>>>(agg, W1, b1, mask, h);
  k_gemm2<<<(NNODES + 63) / 64, 256, 0, stream>>>(h, W2, z);
  k_spmm2<<<(NNODES + 7) / 8, 128, 0, stream>>>(z, offs, deg, ssrc, b2, out);
}

// Round 4
// 281.038 us; speedup vs baseline: 1.1001x; 1.0467x over previous
//
#include <hip/hip_runtime.h>

#define NNODES 50000
#define NEDGES 800000
#define FDIM 128
#define HDIM 128
#define CDIM 16

typedef __attribute__((ext_vector_type(8))) short bf16x8;
typedef __attribute__((ext_vector_type(4))) float f32x4;

// ---------------- CSR build ----------------

__global__ void k_zero_i32(int* __restrict__ p, int n) {
  int i = blockIdx.x * blockDim.x + threadIdx.x;
  if (i < n) p[i] = 0;
}

__global__ void k_count(const int* __restrict__ dst, int* __restrict__ deg, int E) {
  int e = blockIdx.x * blockDim.x + threadIdx.x;
  if (e < E) atomicAdd(&deg[dst[e]], 1);
}

// per-256-chunk exclusive scan; chunk totals into part[]
__global__ void k_scan1(const int* __restrict__ deg, int* __restrict__ offs,
                        int* __restrict__ part, int n) {
  __shared__ int s[256];
  int tid = threadIdx.x;
  int i = blockIdx.x * 256 + tid;
  int v = (i < n) ? deg[i] : 0;
  s[tid] = v;
  for (int off = 1; off < 256; off <<= 1) {
    __syncthreads();
    int t = (tid >= off) ? s[tid - off] : 0;
    __syncthreads();
    s[tid] += t;
  }
  if (i < n) offs[i] = s[tid] - v;            // exclusive within chunk
  if (tid == 255) part[blockIdx.x] = s[255];  // chunk total
}

// exclusive scan of chunk totals (nb <= 256)
__global__ void k_scan2(int* __restrict__ part, int nb) {
  __shared__ int s[256];
  int tid = threadIdx.x;
  int v = (tid < nb) ? part[tid] : 0;
  s[tid] = v;
  for (int off = 1; off < 256; off <<= 1) {
    __syncthreads();
    int t = (tid >= off) ? s[tid - off] : 0;
    __syncthreads();
    s[tid] += t;
  }
  if (tid < nb) part[tid] = s[tid] - v;
}

__global__ void k_scan3(int* __restrict__ offs, const int* __restrict__ part,
                        int* __restrict__ curs, int n) {
  int i = blockIdx.x * blockDim.x + threadIdx.x;
  if (i < n) {
    int o = offs[i] + part[i >> 8];
    offs[i] = o;
    curs[i] = o;
  }
}

__global__ void k_fill(const int* __restrict__ src, const int* __restrict__ dst,
                       int* __restrict__ curs, ushort* __restrict__ ssrc, int E) {
  int e = blockIdx.x * blockDim.x + threadIdx.x;
  if (e < E) {
    int pos = atomicAdd(&curs[dst[e]], 1);
    ssrc[pos] = (ushort)src[e];
  }
}

// ---------------- casts ----------------
__device__ __forceinline__ ushort f32_to_bf16_rne(float f) {
  unsigned u = __float_as_uint(f);
  unsigned rounded = u + 0x7fffu + ((u >> 16) & 1u);
  return (ushort)(rounded >> 16);
}

// x -> bf16, 4 floats per thread
__global__ void k_cast_bf16(const float* __restrict__ x, ushort* __restrict__ xh, int n4) {
  int i = blockIdx.x * blockDim.x + threadIdx.x;
  if (i < n4) {
    float4 v = *reinterpret_cast<const float4*>(&x[i * 4]);
    ushort4 o;
    o.x = f32_to_bf16_rne(v.x);
    o.y = f32_to_bf16_rne(v.y);
    o.z = f32_to_bf16_rne(v.z);
    o.w = f32_to_bf16_rne(v.w);
    *reinterpret_cast<ushort4*>(&xh[i * 4]) = o;
  }
}

// W1[128][128] row-major -> W1T[c][k] bf16
__global__ void k_cast_w1t(const float* __restrict__ W1, ushort* __restrict__ W1T) {
  int t = blockIdx.x * blockDim.x + threadIdx.x;  // 16384 threads
  int c = t >> 7, k = t & 127;
  W1T[c * 128 + k] = f32_to_bf16_rne(W1[k * 128 + c]);
}

// ---------------- layer 1: mean-aggregate bf16 x -> bf16 agg ----------------
// one wave (64 lanes) per node; lane owns channels {2*lane, 2*lane+1}
__global__ __launch_bounds__(256) void k_spmm1(
    const ushort* __restrict__ xh, const int* __restrict__ offs,
    const int* __restrict__ deg, const ushort* __restrict__ ssrc,
    ushort* __restrict__ aggh) {
  int n = blockIdx.x * 4 + (threadIdx.x >> 6);
  if (n >= NNODES) return;
  int lane = threadIdx.x & 63;
  int start = offs[n];
  int d = deg[n];
  float2 acc0 = {0.f, 0.f}, acc1 = {0.f, 0.f};
  float2 acc2 = {0.f, 0.f}, acc3 = {0.f, 0.f};
  int j = 0;
  for (; j + 3 < d; j += 4) {
    int s0 = ssrc[start + j + 0];
    int s1 = ssrc[start + j + 1];
    int s2 = ssrc[start + j + 2];
    int s3 = ssrc[start + j + 3];
    unsigned u0 = *reinterpret_cast<const unsigned*>(&xh[s0 * FDIM + 2 * lane]);
    unsigned u1 = *reinterpret_cast<const unsigned*>(&xh[s1 * FDIM + 2 * lane]);
    unsigned u2 = *reinterpret_cast<const unsigned*>(&xh[s2 * FDIM + 2 * lane]);
    unsigned u3 = *reinterpret_cast<const unsigned*>(&xh[s3 * FDIM + 2 * lane]);
    acc0.x += __uint_as_float(u0 << 16);
    acc0.y += __uint_as_float(u0 & 0xffff0000u);
    acc1.x += __uint_as_float(u1 << 16);
    acc1.y += __uint_as_float(u1 & 0xffff0000u);
    acc2.x += __uint_as_float(u2 << 16);
    acc2.y += __uint_as_float(u2 & 0xffff0000u);
    acc3.x += __uint_as_float(u3 << 16);
    acc3.y += __uint_as_float(u3 & 0xffff0000u);
  }
  for (; j < d; ++j) {
    int s0 = ssrc[start + j];
    unsigned u0 = *reinterpret_cast<const unsigned*>(&xh[s0 * FDIM + 2 * lane]);
    acc0.x += __uint_as_float(u0 << 16);
    acc0.y += __uint_as_float(u0 & 0xffff0000u);
  }
  float inv = 1.0f / (float)(d > 0 ? d : 1);
  float rx = (acc0.x + acc1.x + acc2.x + acc3.x) * inv;
  float ry = (acc0.y + acc1.y + acc2.y + acc3.y) * inv;
  unsigned packed = (unsigned)f32_to_bf16_rne(rx) | ((unsigned)f32_to_bf16_rne(ry) << 16);
  *reinterpret_cast<unsigned*>(&aggh[(size_t)n * FDIM + 2 * lane]) = packed;
}

// ---------------- fused dense via MFMA: h = relu(agg @ W1 + b1) * mask ------
// 256 thr = 4 waves; wave = 16 nodes x 128 cols; no LDS, no barriers.
// A-frag: lane holds A[m=lane&15][k=quad*8+j]; C/D: col=lane&15, row=quad*4+reg.
__global__ __launch_bounds__(256) void k_gemm_fused(
    const ushort* __restrict__ aggh, const ushort* __restrict__ W1T,
    const float* __restrict__ b1, const float* __restrict__ mask,
    float* __restrict__ h) {
  int w = threadIdx.x >> 6;
  int lane = threadIdx.x & 63;
  int nw = blockIdx.x * 64 + w * 16;
  if (nw >= NNODES) return;  // tail wave (NNODES % 64 == 16: whole waves only)
  int l15 = lane & 15, quad = lane >> 4;

  f32x4 acc[8];
  #pragma unroll
  for (int ct = 0; ct < 8; ++ct) acc[ct] = (f32x4){0.f, 0.f, 0.f, 0.f};

  const ushort* arow = &aggh[(size_t)(nw + l15) * 128 + quad * 8];
  #pragma unroll
  for (int kk = 0; kk < 4; ++kk) {
    bf16x8 a = *reinterpret_cast<const bf16x8*>(arow + kk * 32);
    #pragma unroll
    for (int ct = 0; ct < 8; ++ct) {
      bf16x8 b = *reinterpret_cast<const bf16x8*>(
          &W1T[(size_t)(ct * 16 + l15) * 128 + kk * 32 + quad * 8]);
      acc[ct] = __builtin_amdgcn_mfma_f32_16x16x32_bf16(a, b, acc[ct], 0, 0, 0);
    }
  }

  #pragma unroll
  for (int ct = 0; ct < 8; ++ct) {
    int col = ct * 16 + l15;
    float bb = b1[col];
    #pragma unroll
    for (int r = 0; r < 4; ++r) {
      int node = nw + quad * 4 + r;
      float v = acc[ct][r] + bb;
      v = v > 0.f ? v : 0.f;
      v *= mask[(size_t)node * 128 + col];
      h[(size_t)node * 128 + col] = v;
    }
  }
}

// ---------------- z = h @ W2 (N x 128 @ 128 x 16), fp32 ----------------
// 256 thr; thread = (node, col); 16 nodes per block; W2T in LDS
__global__ __launch_bounds__(256) void k_gemm2(
    const float* __restrict__ h, const float* __restrict__ W2,
    float* __restrict__ z) {
  __shared__ float W2T[16 * 132];  // stride 132: 2-way-conflict-free-ish
  int tid = threadIdx.x;
  for (int i = tid; i < 2048; i += 256) {
    int c = i >> 7, k = i & 127;
    W2T[c * 132 + k] = W2[k * 16 + c];
  }
  __syncthreads();
  int n = blockIdx.x * 16 + (tid >> 4);
  int c = tid & 15;
  if (n >= NNODES) return;
  const float4* hp = reinterpret_cast<const float4*>(&h[(size_t)n * 128]);
  const float4* wp = reinterpret_cast<const float4*>(&W2T[c * 132]);
  float acc = 0.f;
  #pragma unroll 8
  for (int k4 = 0; k4 < 32; ++k4) {
    float4 hv = hp[k4];
    float4 wv = wp[k4];
    acc += hv.x * wv.x + hv.y * wv.y + hv.z * wv.z + hv.w * wv.w;
  }
  z[n * 16 + c] = acc;
}

// ---------------- layer 2 aggregate + bias: out = mean(z) + b2 ----------------
// block = 128 threads = 8 nodes x 16 channels
__global__ void k_spmm2(const float* __restrict__ z, const int* __restrict__ offs,
                        const int* __restrict__ deg, const ushort* __restrict__ ssrc,
                        const float* __restrict__ b2, float* __restrict__ out) {
  int tid = threadIdx.x;
  int nl = tid >> 4, c = tid & 15;
  int n = blockIdx.x * 8 + nl;
  if (n >= NNODES) return;
  int start = offs[n], d = deg[n];
  float a0 = 0.f, a1 = 0.f, a2 = 0.f, a3 = 0.f;
  int j = 0;
  for (; j + 3 < d; j += 4) {
    int s0 = ssrc[start + j + 0], s1 = ssrc[start + j + 1];
    int s2 = ssrc[start + j + 2], s3 = ssrc[start + j + 3];
    a0 += z[s0 * 16 + c];
    a1 += z[s1 * 16 + c];
    a2 += z[s2 * 16 + c];
    a3 += z[s3 * 16 + c];
  }
  for (; j < d; ++j) a0 += z[ssrc[start + j] * 16 + c];
  out[n * 16 + c] = (a0 + a1 + a2 + a3) / (float)(d > 0 ? d : 1) + b2[c];
}

// ---------------- launch ----------------

extern "C" void kernel_launch(void* const* d_in, const int* in_sizes, int n_in,
                              void* d_out, int out_size, void* d_ws, size_t ws_size,
                              hipStream_t stream) {
  const float* x    = (const float*)d_in[0];
  const int*   ei   = (const int*)d_in[1];
  const float* W1   = (const float*)d_in[2];
  const float* b1   = (const float*)d_in[3];
  const float* W2   = (const float*)d_in[4];
  const float* b2   = (const float*)d_in[5];
  const float* mask = (const float*)d_in[6];
  float* out = (float*)d_out;

  const int* src = ei;            // edge_index[0]
  const int* dst = ei + NEDGES;   // edge_index[1]

  char* ws = (char*)d_ws;
  size_t o = 0;
  auto alloc = [&](size_t bytes) -> void* {
    void* p = ws + o;
    o += (bytes + 255) & ~(size_t)255;
    return p;
  };
  ushort* aggh = (ushort*)alloc((size_t)NNODES * 128 * 2);
  float*  h    = (float*)alloc((size_t)NNODES * 128 * 4);
  ushort* xh   = (ushort*)alloc((size_t)NNODES * 128 * 2);
  ushort* W1T  = (ushort*)alloc((size_t)128 * 128 * 2);
  int*    deg  = (int*)alloc((size_t)NNODES * 4);
  int*    offs = (int*)alloc((size_t)NNODES * 4);
  int*    curs = (int*)alloc((size_t)NNODES * 4);
  ushort* ssrc = (ushort*)alloc((size_t)NEDGES * 2);
  int*    part = (int*)alloc(256 * 4);
  float*  z    = (float*)aggh;  // overlay: aggh dead after k_gemm_fused (3.2MB <= 12.8MB)

  int NB = (NNODES + 255) / 256;

  k_zero_i32<<<NB, 256, 0, stream>>>(deg, NNODES);
  k_cast_bf16<<<(NNODES * 128 / 4 + 255) / 256, 256, 0, stream>>>(x, xh, NNODES * 128 / 4);
  k_cast_w1t<<<64, 256, 0, stream>>>(W1, W1T);
  k_count<<<(NEDGES + 255) / 256, 256, 0, stream>>>(dst, deg, NEDGES);
  k_scan1<<<NB, 256, 0, stream>>>(deg, offs, part, NNODES);
  k_scan2<<<1, 256, 0, stream>>>(part, NB);
  k_scan3<<<NB, 256, 0, stream>>>(offs, part, curs, NNODES);
  k_fill<<<(NEDGES + 255) / 256, 256, 0, stream>>>(src, dst, curs, ssrc, NEDGES);
  k_spmm1<<<(NNODES + 3) / 4, 256, 0, stream>>>(xh, offs, deg, ssrc, aggh);
  k_gemm_fused<<<(NNODES + 63) / 64, 256, 0, stream>>>(aggh, W1T, b1, mask, h);
  k_gemm2<<<(NNODES + 15) / 16, 256, 0, stream>>>(h, W2, z);
  k_spmm2<<<(NNODES + 7) / 8, 128, 0, stream>>>(z, offs, deg, ssrc, b2, out);
}

// Round 5
// 250.481 us; speedup vs baseline: 1.2343x; 1.1220x over previous
//
#include <hip/hip_runtime.h>

#define NNODES 50000
#define NEDGES 800000
#define FDIM 128
#define HDIM 128
#define CDIM 16

typedef __attribute__((ext_vector_type(8))) short bf16x8;
typedef __attribute__((ext_vector_type(4))) float f32x4;

__device__ __forceinline__ ushort f32_to_bf16_rne(float f) {
  unsigned u = __float_as_uint(f);
  unsigned rounded = u + 0x7fffu + ((u >> 16) & 1u);
  return (ushort)(rounded >> 16);
}

// ---------------- prep: zero deg + cast x->bf16 + W1T + W2T ----------------
// ranges: [0,1600000) cast x (4 floats each); [..+16384) W1T; [..+2048) W2T; [..+50000) zero deg
__global__ void k_prep(const float* __restrict__ x, ushort* __restrict__ xh,
                       const float* __restrict__ W1, ushort* __restrict__ W1T,
                       const float* __restrict__ W2, ushort* __restrict__ W2T,
                       int* __restrict__ deg) {
  int t = blockIdx.x * blockDim.x + threadIdx.x;
  if (t < 1600000) {
    float4 v = *reinterpret_cast<const float4*>(&x[t * 4]);
    ushort4 o;
    o.x = f32_to_bf16_rne(v.x);
    o.y = f32_to_bf16_rne(v.y);
    o.z = f32_to_bf16_rne(v.z);
    o.w = f32_to_bf16_rne(v.w);
    *reinterpret_cast<ushort4*>(&xh[t * 4]) = o;
    return;
  }
  t -= 1600000;
  if (t < 16384) {  // W1T[c][k] = bf16(W1[k][c])
    int c = t >> 7, k = t & 127;
    W1T[c * 128 + k] = f32_to_bf16_rne(W1[k * 128 + c]);
    return;
  }
  t -= 16384;
  if (t < 2048) {  // W2T[c][k] = bf16(W2[k][c])
    int c = t >> 7, k = t & 127;
    W2T[c * 128 + k] = f32_to_bf16_rne(W2[k * 16 + c]);
    return;
  }
  t -= 2048;
  if (t < NNODES) deg[t] = 0;
}

// ---------------- CSR build ----------------

__global__ void k_count(const int* __restrict__ dst, int* __restrict__ deg, int E) {
  int e = blockIdx.x * blockDim.x + threadIdx.x;
  if (e < E) atomicAdd(&deg[dst[e]], 1);
}

// per-256-chunk exclusive scan; chunk totals into part[]
__global__ void k_scan1(const int* __restrict__ deg, int* __restrict__ offs,
                        int* __restrict__ part, int n) {
  __shared__ int s[256];
  int tid = threadIdx.x;
  int i = blockIdx.x * 256 + tid;
  int v = (i < n) ? deg[i] : 0;
  s[tid] = v;
  for (int off = 1; off < 256; off <<= 1) {
    __syncthreads();
    int t = (tid >= off) ? s[tid - off] : 0;
    __syncthreads();
    s[tid] += t;
  }
  if (i < n) offs[i] = s[tid] - v;            // exclusive within chunk
  if (tid == 255) part[blockIdx.x] = s[255];  // chunk total
}

// fused scan2+scan3: each block reduces part[0..blockIdx) then adds to its chunk
__global__ void k_scan23(int* __restrict__ offs, const int* __restrict__ part,
                         int* __restrict__ curs, int n, int nb) {
  __shared__ int s[256];
  int tid = threadIdx.x;
  int b = blockIdx.x;
  s[tid] = (tid < b && tid < nb) ? part[tid] : 0;
  __syncthreads();
  #pragma unroll
  for (int off = 128; off > 0; off >>= 1) {
    if (tid < off) s[tid] += s[tid + off];
    __syncthreads();
  }
  int base = s[0];
  int i = b * 256 + tid;
  if (i < n) {
    int o = offs[i] + base;
    offs[i] = o;
    curs[i] = o;
  }
}

__global__ void k_fill(const int* __restrict__ src, const int* __restrict__ dst,
                       int* __restrict__ curs, ushort* __restrict__ ssrc, int E) {
  int e = blockIdx.x * blockDim.x + threadIdx.x;
  if (e < E) {
    int pos = atomicAdd(&curs[dst[e]], 1);
    ssrc[pos] = (ushort)src[e];
  }
}

// ---------------- layer 1: mean-aggregate bf16 x -> bf16 agg ----------------
// one wave (64 lanes) per node; lane owns channels {2*lane, 2*lane+1}
__global__ __launch_bounds__(256) void k_spmm1(
    const ushort* __restrict__ xh, const int* __restrict__ offs,
    const int* __restrict__ deg, const ushort* __restrict__ ssrc,
    ushort* __restrict__ aggh) {
  int n = blockIdx.x * 4 + (threadIdx.x >> 6);
  if (n >= NNODES) return;
  int lane = threadIdx.x & 63;
  int start = offs[n];
  int d = deg[n];
  float2 acc0 = {0.f, 0.f}, acc1 = {0.f, 0.f};
  float2 acc2 = {0.f, 0.f}, acc3 = {0.f, 0.f};
  int j = 0;
  for (; j + 3 < d; j += 4) {
    int s0 = ssrc[start + j + 0];
    int s1 = ssrc[start + j + 1];
    int s2 = ssrc[start + j + 2];
    int s3 = ssrc[start + j + 3];
    unsigned u0 = *reinterpret_cast<const unsigned*>(&xh[s0 * FDIM + 2 * lane]);
    unsigned u1 = *reinterpret_cast<const unsigned*>(&xh[s1 * FDIM + 2 * lane]);
    unsigned u2 = *reinterpret_cast<const unsigned*>(&xh[s2 * FDIM + 2 * lane]);
    unsigned u3 = *reinterpret_cast<const unsigned*>(&xh[s3 * FDIM + 2 * lane]);
    acc0.x += __uint_as_float(u0 << 16);
    acc0.y += __uint_as_float(u0 & 0xffff0000u);
    acc1.x += __uint_as_float(u1 << 16);
    acc1.y += __uint_as_float(u1 & 0xffff0000u);
    acc2.x += __uint_as_float(u2 << 16);
    acc2.y += __uint_as_float(u2 & 0xffff0000u);
    acc3.x += __uint_as_float(u3 << 16);
    acc3.y += __uint_as_float(u3 & 0xffff0000u);
  }
  for (; j < d; ++j) {
    int s0 = ssrc[start + j];
    unsigned u0 = *reinterpret_cast<const unsigned*>(&xh[s0 * FDIM + 2 * lane]);
    acc0.x += __uint_as_float(u0 << 16);
    acc0.y += __uint_as_float(u0 & 0xffff0000u);
  }
  float inv = 1.0f / (float)(d > 0 ? d : 1);
  float rx = (acc0.x + acc1.x + acc2.x + acc3.x) * inv;
  float ry = (acc0.y + acc1.y + acc2.y + acc3.y) * inv;
  unsigned packed = (unsigned)f32_to_bf16_rne(rx) | ((unsigned)f32_to_bf16_rne(ry) << 16);
  *reinterpret_cast<unsigned*>(&aggh[(size_t)n * FDIM + 2 * lane]) = packed;
}

// ---------------- fused dense: z = (relu(agg@W1+b1)*mask) @ W2 ----------------
// 256 thr = 4 waves; wave = 16 nodes; h-tile lives only in LDS (bf16).
// A-frag: lane holds A[m=lane&15][k=quad*8+j]; C/D: col=lane&15, row=quad*4+reg.
#define HT_STRIDE 132  // shorts; 264B rows: ds b16/b64 accesses are 2-way aliased (free)
__global__ __launch_bounds__(256) void k_dense(
    const ushort* __restrict__ aggh, const ushort* __restrict__ W1T,
    const float* __restrict__ b1, const float* __restrict__ mask,
    const ushort* __restrict__ W2T, float* __restrict__ z) {
  __shared__ ushort hT[4][16 * HT_STRIDE];
  int w = threadIdx.x >> 6;
  int lane = threadIdx.x & 63;
  int nw = blockIdx.x * 64 + w * 16;
  if (nw >= NNODES) return;  // whole-wave tail (NNODES % 16 == 0)
  int l15 = lane & 15, quad = lane >> 4;

  f32x4 acc[8];
  #pragma unroll
  for (int ct = 0; ct < 8; ++ct) acc[ct] = (f32x4){0.f, 0.f, 0.f, 0.f};

  const ushort* arow = &aggh[(size_t)(nw + l15) * 128 + quad * 8];
  #pragma unroll
  for (int kk = 0; kk < 4; ++kk) {
    bf16x8 a = *reinterpret_cast<const bf16x8*>(arow + kk * 32);
    #pragma unroll
    for (int ct = 0; ct < 8; ++ct) {
      bf16x8 b = *reinterpret_cast<const bf16x8*>(
          &W1T[(size_t)(ct * 16 + l15) * 128 + kk * 32 + quad * 8]);
      acc[ct] = __builtin_amdgcn_mfma_f32_16x16x32_bf16(a, b, acc[ct], 0, 0, 0);
    }
  }

  // epilogue: +b1, relu, *mask -> bf16 LDS tile [row=node_local][col]
  ushort* ht = hT[w];
  #pragma unroll
  for (int ct = 0; ct < 8; ++ct) {
    int col = ct * 16 + l15;
    float bb = b1[col];
    #pragma unroll
    for (int r = 0; r < 4; ++r) {
      int node = nw + quad * 4 + r;
      float v = acc[ct][r] + bb;
      v = v > 0.f ? v : 0.f;
      v *= mask[(size_t)node * 128 + col];
      ht[(quad * 4 + r) * HT_STRIDE + col] = f32_to_bf16_rne(v);
    }
  }
  // wave-private tile: no __syncthreads needed (compiler inserts lgkmcnt)

  // second GEMM: z_tile[16n x 16c] = hT @ W2  (4 x K=32 MFMA steps)
  f32x4 zacc = (f32x4){0.f, 0.f, 0.f, 0.f};
  #pragma unroll
  for (int kk = 0; kk < 4; ++kk) {
    const ushort* ap = &ht[l15 * HT_STRIDE + kk * 32 + quad * 8];
    ushort4 alo = *reinterpret_cast<const ushort4*>(ap);      // 8B-aligned LDS reads
    ushort4 ahi = *reinterpret_cast<const ushort4*>(ap + 4);
    bf16x8 a2 = (bf16x8){(short)alo.x, (short)alo.y, (short)alo.z, (short)alo.w,
                         (short)ahi.x, (short)ahi.y, (short)ahi.z, (short)ahi.w};
    bf16x8 b2 = *reinterpret_cast<const bf16x8*>(&W2T[l15 * 128 + kk * 32 + quad * 8]);
    zacc = __builtin_amdgcn_mfma_f32_16x16x32_bf16(a2, b2, zacc, 0, 0, 0);
  }
  #pragma unroll
  for (int r = 0; r < 4; ++r) {
    z[(size_t)(nw + quad * 4 + r) * 16 + l15] = zacc[r];
  }
}

// ---------------- layer 2 aggregate + bias: out = mean(z) + b2 ----------------
// block = 128 threads = 8 nodes x 16 channels
__global__ void k_spmm2(const float* __restrict__ z, const int* __restrict__ offs,
                        const int* __restrict__ deg, const ushort* __restrict__ ssrc,
                        const float* __restrict__ b2, float* __restrict__ out) {
  int tid = threadIdx.x;
  int nl = tid >> 4, c = tid & 15;
  int n = blockIdx.x * 8 + nl;
  if (n >= NNODES) return;
  int start = offs[n], d = deg[n];
  float a0 = 0.f, a1 = 0.f, a2 = 0.f, a3 = 0.f;
  int j = 0;
  for (; j + 3 < d; j += 4) {
    int s0 = ssrc[start + j + 0], s1 = ssrc[start + j + 1];
    int s2 = ssrc[start + j + 2], s3 = ssrc[start + j + 3];
    a0 += z[s0 * 16 + c];
    a1 += z[s1 * 16 + c];
    a2 += z[s2 * 16 + c];
    a3 += z[s3 * 16 + c];
  }
  for (; j < d; ++j) a0 += z[ssrc[start + j] * 16 + c];
  out[n * 16 + c] = (a0 + a1 + a2 + a3) / (float)(d > 0 ? d : 1) + b2[c];
}

// ---------------- launch ----------------

extern "C" void kernel_launch(void* const* d_in, const int* in_sizes, int n_in,
                              void* d_out, int out_size, void* d_ws, size_t ws_size,
                              hipStream_t stream) {
  const float* x    = (const float*)d_in[0];
  const int*   ei   = (const int*)d_in[1];
  const float* W1   = (const float*)d_in[2];
  const float* b1   = (const float*)d_in[3];
  const float* W2   = (const float*)d_in[4];
  const float* b2   = (const float*)d_in[5];
  const float* mask = (const float*)d_in[6];
  float* out = (float*)d_out;

  const int* src = ei;            // edge_index[0]
  const int* dst = ei + NEDGES;   // edge_index[1]

  char* ws = (char*)d_ws;
  size_t o = 0;
  auto alloc = [&](size_t bytes) -> void* {
    void* p = ws + o;
    o += (bytes + 255) & ~(size_t)255;
    return p;
  };
  ushort* aggh = (ushort*)alloc((size_t)NNODES * 128 * 2);
  ushort* xh   = (ushort*)alloc((size_t)NNODES * 128 * 2);
  float*  z    = (float*)alloc((size_t)NNODES * 16 * 4);
  ushort* W1T  = (ushort*)alloc((size_t)128 * 128 * 2);
  ushort* W2T  = (ushort*)alloc((size_t)16 * 128 * 2);
  int*    deg  = (int*)alloc((size_t)NNODES * 4);
  int*    offs = (int*)alloc((size_t)NNODES * 4);
  int*    curs = (int*)alloc((size_t)NNODES * 4);
  ushort* ssrc = (ushort*)alloc((size_t)NEDGES * 2);
  int*    part = (int*)alloc(256 * 4);

  int NB = (NNODES + 255) / 256;
  int prep_threads = 1600000 + 16384 + 2048 + NNODES;

  k_prep<<<(prep_threads + 255) / 256, 256, 0, stream>>>(x, xh, W1, W1T, W2, W2T, deg);
  k_count<<<(NEDGES + 255) / 256, 256, 0, stream>>>(dst, deg, NEDGES);
  k_scan1<<<NB, 256, 0, stream>>>(deg, offs, part, NNODES);
  k_scan23<<<NB, 256, 0, stream>>>(offs, part, curs, NNODES, NB);
  k_fill<<<(NEDGES + 255) / 256, 256, 0, stream>>>(src, dst, curs, ssrc, NEDGES);
  k_spmm1<<<(NNODES + 3) / 4, 256, 0, stream>>>(xh, offs, deg, ssrc, aggh);
  k_dense<<<(NNODES + 63) / 64, 256, 0, stream>>>(aggh, W1T, b1, mask, W2T, z);
  k_spmm2<<<(NNODES + 7) / 8, 128, 0, stream>>>(z, offs, deg, ssrc, b2, out);
}

// Round 6
// 193.653 us; speedup vs baseline: 1.5966x; 1.2935x over previous
//
#include <hip/hip_runtime.h>

#define NNODES 50000
#define NEDGES 800000
#define FDIM 128
#define HDIM 128
#define CDIM 16

#define NBUCK 256
#define BCAP 6144  // per-bucket capacity: mean 4096, sd 64 -> 32 sigma headroom

typedef __attribute__((ext_vector_type(8))) short bf16x8;
typedef __attribute__((ext_vector_type(4))) float f32x4;

__device__ __forceinline__ ushort f32_to_bf16_rne(float f) {
  unsigned u = __float_as_uint(f);
  unsigned rounded = u + 0x7fffu + ((u >> 16) & 1u);
  return (ushort)(rounded >> 16);
}

// ---------------- prep: cast x->bf16 + W1T + W2T + init gcur ----------------
__global__ void k_prep(const float* __restrict__ x, ushort* __restrict__ xh,
                       const float* __restrict__ W1, ushort* __restrict__ W1T,
                       const float* __restrict__ W2, ushort* __restrict__ W2T,
                       int* __restrict__ gcur) {
  int t = blockIdx.x * blockDim.x + threadIdx.x;
  if (t < 1600000) {
    float4 v = *reinterpret_cast<const float4*>(&x[t * 4]);
    ushort4 o;
    o.x = f32_to_bf16_rne(v.x);
    o.y = f32_to_bf16_rne(v.y);
    o.z = f32_to_bf16_rne(v.z);
    o.w = f32_to_bf16_rne(v.w);
    *reinterpret_cast<ushort4*>(&xh[t * 4]) = o;
    return;
  }
  t -= 1600000;
  if (t < 16384) {  // W1T[c][k] = bf16(W1[k][c])
    int c = t >> 7, k = t & 127;
    W1T[c * 128 + k] = f32_to_bf16_rne(W1[k * 128 + c]);
    return;
  }
  t -= 16384;
  if (t < 2048) {  // W2T[c][k] = bf16(W2[k][c])
    int c = t >> 7, k = t & 127;
    W2T[c * 128 + k] = f32_to_bf16_rne(W2[k * 16 + c]);
    return;
  }
  t -= 2048;
  if (t < NBUCK) gcur[t] = t * BCAP;
}

// ---------------- phase A: bucket edges by dst>>8 ----------------
// block = 256 thr x 8 edges; LDS histogram -> one global reserve per bucket ->
// contiguous packed writes. ebuf entry: (dst&255)<<16 | src
__global__ __launch_bounds__(256) void k_binA(
    const int* __restrict__ src, const int* __restrict__ dst,
    int* __restrict__ gcur, unsigned* __restrict__ ebuf) {
  __shared__ int cnt[NBUCK];
  __shared__ int base[NBUCK];
  int tid = threadIdx.x;
  int e0 = blockIdx.x * 2048;
  cnt[tid] = 0;
  __syncthreads();
  int sv[8], dv[8];
  #pragma unroll
  for (int i = 0; i < 8; ++i) {
    int e = e0 + i * 256 + tid;
    if (e < NEDGES) {
      sv[i] = src[e];
      dv[i] = dst[e];
      atomicAdd(&cnt[dv[i] >> 8], 1);
    } else {
      dv[i] = -1;
    }
  }
  __syncthreads();
  base[tid] = atomicAdd(&gcur[tid], cnt[tid]);
  cnt[tid] = 0;  // reuse as local cursor
  __syncthreads();
  #pragma unroll
  for (int i = 0; i < 8; ++i) {
    if (dv[i] >= 0) {
      int b = dv[i] >> 8;
      int pos = base[b] + atomicAdd(&cnt[b], 1);
      if (pos < (b + 1) * BCAP)  // safety clamp (statistically impossible)
        ebuf[pos] = ((unsigned)(dv[i] & 255) << 16) | (unsigned)sv[i];
    }
  }
}

// ---------------- phase B: per-bucket CSR finalize (all atomics in LDS) -----
// one block per bucket; writes deg/offs coalesced, ssrc into bucket's window
__global__ __launch_bounds__(256) void k_binB(
    const int* __restrict__ gcur, const unsigned* __restrict__ ebuf,
    int* __restrict__ deg, int* __restrict__ offs, ushort* __restrict__ ssrc) {
  __shared__ int s[NBUCK];
  __shared__ int doff[NBUCK];
  __shared__ int dcur[NBUCK];
  int tid = threadIdx.x;
  int b = blockIdx.x;

  // bucket counts + exclusive scan -> my bucket's global base
  int c = gcur[tid] - tid * BCAP;
  if (c > BCAP) c = BCAP;
  int myc = 0;
  s[tid] = c;
  for (int off = 1; off < 256; off <<= 1) {
    __syncthreads();
    int t = (tid >= off) ? s[tid - off] : 0;
    __syncthreads();
    s[tid] += t;
  }
  __syncthreads();
  int my_base = (b > 0) ? s[b - 1] : 0;  // exclusive prefix
  int count = s[b] - my_base;

  // per-node histogram within bucket
  dcur[tid] = 0;
  __syncthreads();
  const unsigned* eb = &ebuf[b * BCAP];
  for (int e = tid; e < count; e += 256) {
    atomicAdd(&dcur[eb[e] >> 16], 1);
  }
  __syncthreads();
  int dn = dcur[tid];
  s[tid] = dn;
  for (int off = 1; off < 256; off <<= 1) {
    __syncthreads();
    int t = (tid >= off) ? s[tid - off] : 0;
    __syncthreads();
    s[tid] += t;
  }
  __syncthreads();
  doff[tid] = s[tid] - dn;  // exclusive within bucket
  int node = b * 256 + tid;
  if (node < NNODES) {
    deg[node] = dn;
    offs[node] = my_base + doff[tid];
  }
  dcur[tid] = 0;
  __syncthreads();

  // scatter src ids into CSR order (bucket-local ~8KB window)
  for (int e = tid; e < count; e += 256) {
    unsigned v = eb[e];
    int loc = v >> 16;
    int pos = my_base + doff[loc] + atomicAdd(&dcur[loc], 1);
    ssrc[pos] = (ushort)(v & 0xffffu);
  }
}

// ---------------- layer 1: mean-aggregate bf16 x -> bf16 agg ----------------
// one wave (64 lanes) per node; lane owns channels {2*lane, 2*lane+1}
__global__ __launch_bounds__(256) void k_spmm1(
    const ushort* __restrict__ xh, const int* __restrict__ offs,
    const int* __restrict__ deg, const ushort* __restrict__ ssrc,
    ushort* __restrict__ aggh) {
  int n = blockIdx.x * 4 + (threadIdx.x >> 6);
  if (n >= NNODES) return;
  int lane = threadIdx.x & 63;
  int start = offs[n];
  int d = deg[n];
  float2 acc0 = {0.f, 0.f}, acc1 = {0.f, 0.f};
  float2 acc2 = {0.f, 0.f}, acc3 = {0.f, 0.f};
  int j = 0;
  for (; j + 3 < d; j += 4) {
    int s0 = ssrc[start + j + 0];
    int s1 = ssrc[start + j + 1];
    int s2 = ssrc[start + j + 2];
    int s3 = ssrc[start + j + 3];
    unsigned u0 = *reinterpret_cast<const unsigned*>(&xh[s0 * FDIM + 2 * lane]);
    unsigned u1 = *reinterpret_cast<const unsigned*>(&xh[s1 * FDIM + 2 * lane]);
    unsigned u2 = *reinterpret_cast<const unsigned*>(&xh[s2 * FDIM + 2 * lane]);
    unsigned u3 = *reinterpret_cast<const unsigned*>(&xh[s3 * FDIM + 2 * lane]);
    acc0.x += __uint_as_float(u0 << 16);
    acc0.y += __uint_as_float(u0 & 0xffff0000u);
    acc1.x += __uint_as_float(u1 << 16);
    acc1.y += __uint_as_float(u1 & 0xffff0000u);
    acc2.x += __uint_as_float(u2 << 16);
    acc2.y += __uint_as_float(u2 & 0xffff0000u);
    acc3.x += __uint_as_float(u3 << 16);
    acc3.y += __uint_as_float(u3 & 0xffff0000u);
  }
  for (; j < d; ++j) {
    int s0 = ssrc[start + j];
    unsigned u0 = *reinterpret_cast<const unsigned*>(&xh[s0 * FDIM + 2 * lane]);
    acc0.x += __uint_as_float(u0 << 16);
    acc0.y += __uint_as_float(u0 & 0xffff0000u);
  }
  float inv = 1.0f / (float)(d > 0 ? d : 1);
  float rx = (acc0.x + acc1.x + acc2.x + acc3.x) * inv;
  float ry = (acc0.y + acc1.y + acc2.y + acc3.y) * inv;
  unsigned packed = (unsigned)f32_to_bf16_rne(rx) | ((unsigned)f32_to_bf16_rne(ry) << 16);
  *reinterpret_cast<unsigned*>(&aggh[(size_t)n * FDIM + 2 * lane]) = packed;
}

// ---------------- fused dense: z = (relu(agg@W1+b1)*mask) @ W2 ----------------
// 256 thr = 4 waves; wave = 16 nodes; h-tile lives only in LDS (bf16).
// A-frag: lane holds A[m=lane&15][k=quad*8+j]; C/D: col=lane&15, row=quad*4+reg.
#define HT_STRIDE 132  // shorts; ds b16/b64 accesses are 2-way aliased (free)
__global__ __launch_bounds__(256) void k_dense(
    const ushort* __restrict__ aggh, const ushort* __restrict__ W1T,
    const float* __restrict__ b1, const float* __restrict__ mask,
    const ushort* __restrict__ W2T, float* __restrict__ z) {
  __shared__ ushort hT[4][16 * HT_STRIDE];
  int w = threadIdx.x >> 6;
  int lane = threadIdx.x & 63;
  int nw = blockIdx.x * 64 + w * 16;
  if (nw >= NNODES) return;  // whole-wave tail (NNODES % 16 == 0)
  int l15 = lane & 15, quad = lane >> 4;

  f32x4 acc[8];
  #pragma unroll
  for (int ct = 0; ct < 8; ++ct) acc[ct] = (f32x4){0.f, 0.f, 0.f, 0.f};

  const ushort* arow = &aggh[(size_t)(nw + l15) * 128 + quad * 8];
  #pragma unroll
  for (int kk = 0; kk < 4; ++kk) {
    bf16x8 a = *reinterpret_cast<const bf16x8*>(arow + kk * 32);
    #pragma unroll
    for (int ct = 0; ct < 8; ++ct) {
      bf16x8 b = *reinterpret_cast<const bf16x8*>(
          &W1T[(size_t)(ct * 16 + l15) * 128 + kk * 32 + quad * 8]);
      acc[ct] = __builtin_amdgcn_mfma_f32_16x16x32_bf16(a, b, acc[ct], 0, 0, 0);
    }
  }

  // epilogue: +b1, relu, *mask -> bf16 LDS tile [row=node_local][col]
  ushort* ht = hT[w];
  #pragma unroll
  for (int ct = 0; ct < 8; ++ct) {
    int col = ct * 16 + l15;
    float bb = b1[col];
    #pragma unroll
    for (int r = 0; r < 4; ++r) {
      int node = nw + quad * 4 + r;
      float v = acc[ct][r] + bb;
      v = v > 0.f ? v : 0.f;
      v *= mask[(size_t)node * 128 + col];
      ht[(quad * 4 + r) * HT_STRIDE + col] = f32_to_bf16_rne(v);
    }
  }
  // wave-private tile: no __syncthreads needed (compiler inserts lgkmcnt)

  // second GEMM: z_tile[16n x 16c] = hT @ W2  (4 x K=32 MFMA steps)
  f32x4 zacc = (f32x4){0.f, 0.f, 0.f, 0.f};
  #pragma unroll
  for (int kk = 0; kk < 4; ++kk) {
    const ushort* ap = &ht[l15 * HT_STRIDE + kk * 32 + quad * 8];
    ushort4 alo = *reinterpret_cast<const ushort4*>(ap);      // 8B-aligned LDS reads
    ushort4 ahi = *reinterpret_cast<const ushort4*>(ap + 4);
    bf16x8 a2 = (bf16x8){(short)alo.x, (short)alo.y, (short)alo.z, (short)alo.w,
                         (short)ahi.x, (short)ahi.y, (short)ahi.z, (short)ahi.w};
    bf16x8 b2 = *reinterpret_cast<const bf16x8*>(&W2T[l15 * 128 + kk * 32 + quad * 8]);
    zacc = __builtin_amdgcn_mfma_f32_16x16x32_bf16(a2, b2, zacc, 0, 0, 0);
  }
  #pragma unroll
  for (int r = 0; r < 4; ++r) {
    z[(size_t)(nw + quad * 4 + r) * 16 + l15] = zacc[r];
  }
}

// ---------------- layer 2 aggregate + bias: out = mean(z) + b2 ----------------
// block = 128 threads = 8 nodes x 16 channels
__global__ void k_spmm2(const float* __restrict__ z, const int* __restrict__ offs,
                        const int* __restrict__ deg, const ushort* __restrict__ ssrc,
                        const float* __restrict__ b2, float* __restrict__ out) {
  int tid = threadIdx.x;
  int nl = tid >> 4, c = tid & 15;
  int n = blockIdx.x * 8 + nl;
  if (n >= NNODES) return;
  int start = offs[n], d = deg[n];
  float a0 = 0.f, a1 = 0.f, a2 = 0.f, a3 = 0.f;
  int j = 0;
  for (; j + 3 < d; j += 4) {
    int s0 = ssrc[start + j + 0], s1 = ssrc[start + j + 1];
    int s2 = ssrc[start + j + 2], s3 = ssrc[start + j + 3];
    a0 += z[s0 * 16 + c];
    a1 += z[s1 * 16 + c];
    a2 += z[s2 * 16 + c];
    a3 += z[s3 * 16 + c];
  }
  for (; j < d; ++j) a0 += z[ssrc[start + j] * 16 + c];
  out[n * 16 + c] = (a0 + a1 + a2 + a3) / (float)(d > 0 ? d : 1) + b2[c];
}

// ---------------- launch ----------------

extern "C" void kernel_launch(void* const* d_in, const int* in_sizes, int n_in,
                              void* d_out, int out_size, void* d_ws, size_t ws_size,
                              hipStream_t stream) {
  const float* x    = (const float*)d_in[0];
  const int*   ei   = (const int*)d_in[1];
  const float* W1   = (const float*)d_in[2];
  const float* b1   = (const float*)d_in[3];
  const float* W2   = (const float*)d_in[4];
  const float* b2   = (const float*)d_in[5];
  const float* mask = (const float*)d_in[6];
  float* out = (float*)d_out;

  const int* src = ei;            // edge_index[0]
  const int* dst = ei + NEDGES;   // edge_index[1]

  char* ws = (char*)d_ws;
  size_t o = 0;
  auto alloc = [&](size_t bytes) -> void* {
    void* p = ws + o;
    o += (bytes + 255) & ~(size_t)255;
    return p;
  };
  ushort*   aggh = (ushort*)alloc((size_t)NNODES * 128 * 2);
  ushort*   xh   = (ushort*)alloc((size_t)NNODES * 128 * 2);
  float*    z    = (float*)alloc((size_t)NNODES * 16 * 4);
  ushort*   W1T  = (ushort*)alloc((size_t)128 * 128 * 2);
  ushort*   W2T  = (ushort*)alloc((size_t)16 * 128 * 2);
  int*      deg  = (int*)alloc((size_t)NNODES * 4);
  int*      offs = (int*)alloc((size_t)NNODES * 4);
  int*      gcur = (int*)alloc((size_t)NBUCK * 4);
  unsigned* ebuf = (unsigned*)alloc((size_t)NBUCK * BCAP * 4);
  ushort*   ssrc = (ushort*)alloc((size_t)NEDGES * 2);

  int prep_threads = 1600000 + 16384 + 2048 + NBUCK;

  k_prep<<<(prep_threads + 255) / 256, 256, 0, stream>>>(x, xh, W1, W1T, W2, W2T, gcur);
  k_binA<<<(NEDGES + 2047) / 2048, 256, 0, stream>>>(src, dst, gcur, ebuf);
  k_binB<<<NBUCK, 256, 0, stream>>>(gcur, ebuf, deg, offs, ssrc);
  k_spmm1<<<(NNODES + 3) / 4, 256, 0, stream>>>(xh, offs, deg, ssrc, aggh);
  k_dense<<<(NNODES + 63) / 64, 256, 0, stream>>>(aggh, W1T, b1, mask, W2T, z);
  k_spmm2<<<(NNODES + 7) / 8, 128, 0, stream>>>(z, offs, deg, ssrc, b2, out);
}

// Round 7
// 186.958 us; speedup vs baseline: 1.6537x; 1.0358x over previous
//
#include <hip/hip_runtime.h>

#define NNODES 50000
#define NEDGES 800000
#define FDIM 128
#define HDIM 128
#define CDIM 16

#define NBUCK 256
#define BCAP 6144  // per-bucket capacity: mean 4096, sd 64 -> 32 sigma headroom

typedef __attribute__((ext_vector_type(8))) short bf16x8;
typedef __attribute__((ext_vector_type(4))) float f32x4;

__device__ __forceinline__ ushort f32_to_bf16_rne(float f) {
  unsigned u = __float_as_uint(f);
  unsigned rounded = u + 0x7fffu + ((u >> 16) & 1u);
  return (ushort)(rounded >> 16);
}

// ---------------- prep: cast x->bf16 + W1T + W2T + init gcur ----------------
__global__ void k_prep(const float* __restrict__ x, ushort* __restrict__ xh,
                       const float* __restrict__ W1, ushort* __restrict__ W1T,
                       const float* __restrict__ W2, ushort* __restrict__ W2T,
                       int* __restrict__ gcur) {
  int t = blockIdx.x * blockDim.x + threadIdx.x;
  if (t < 1600000) {
    float4 v = *reinterpret_cast<const float4*>(&x[t * 4]);
    ushort4 o;
    o.x = f32_to_bf16_rne(v.x);
    o.y = f32_to_bf16_rne(v.y);
    o.z = f32_to_bf16_rne(v.z);
    o.w = f32_to_bf16_rne(v.w);
    *reinterpret_cast<ushort4*>(&xh[t * 4]) = o;
    return;
  }
  t -= 1600000;
  if (t < 16384) {  // W1T[c][k] = bf16(W1[k][c])
    int c = t >> 7, k = t & 127;
    W1T[c * 128 + k] = f32_to_bf16_rne(W1[k * 128 + c]);
    return;
  }
  t -= 16384;
  if (t < 2048) {  // W2T[c][k] = bf16(W2[k][c])
    int c = t >> 7, k = t & 127;
    W2T[c * 128 + k] = f32_to_bf16_rne(W2[k * 16 + c]);
    return;
  }
  t -= 2048;
  if (t < NBUCK) gcur[t] = t * BCAP;
}

// ---------------- phase A: bucket edges by dst>>8 ----------------
// block = 256 thr x 8 edges; LDS histogram -> one global reserve per bucket ->
// contiguous packed writes. ebuf entry: (dst&255)<<16 | src
__global__ __launch_bounds__(256) void k_binA(
    const int* __restrict__ src, const int* __restrict__ dst,
    int* __restrict__ gcur, unsigned* __restrict__ ebuf) {
  __shared__ int cnt[NBUCK];
  __shared__ int base[NBUCK];
  int tid = threadIdx.x;
  int e0 = blockIdx.x * 2048;
  cnt[tid] = 0;
  __syncthreads();
  int sv[8], dv[8];
  #pragma unroll
  for (int i = 0; i < 8; ++i) {
    int e = e0 + i * 256 + tid;
    if (e < NEDGES) {
      sv[i] = src[e];
      dv[i] = dst[e];
      atomicAdd(&cnt[dv[i] >> 8], 1);
    } else {
      dv[i] = -1;
    }
  }
  __syncthreads();
  base[tid] = atomicAdd(&gcur[tid], cnt[tid]);
  cnt[tid] = 0;  // reuse as local cursor
  __syncthreads();
  #pragma unroll
  for (int i = 0; i < 8; ++i) {
    if (dv[i] >= 0) {
      int b = dv[i] >> 8;
      int pos = base[b] + atomicAdd(&cnt[b], 1);
      if (pos < (b + 1) * BCAP)  // safety clamp (statistically impossible)
        ebuf[pos] = ((unsigned)(dv[i] & 255) << 16) | (unsigned)sv[i];
    }
  }
}

// ---------------- phase B: per-bucket CSR finalize (all atomics in LDS) -----
// one block per bucket; writes deg/offs coalesced, ssrc into bucket's window
__global__ __launch_bounds__(256) void k_binB(
    const int* __restrict__ gcur, const unsigned* __restrict__ ebuf,
    int* __restrict__ deg, int* __restrict__ offs, ushort* __restrict__ ssrc) {
  __shared__ int s[NBUCK];
  __shared__ int doff[NBUCK];
  __shared__ int dcur[NBUCK];
  int tid = threadIdx.x;
  int b = blockIdx.x;

  // bucket counts + exclusive scan -> my bucket's global base
  int c = gcur[tid] - tid * BCAP;
  if (c > BCAP) c = BCAP;
  s[tid] = c;
  for (int off = 1; off < 256; off <<= 1) {
    __syncthreads();
    int t = (tid >= off) ? s[tid - off] : 0;
    __syncthreads();
    s[tid] += t;
  }
  __syncthreads();
  int my_base = (b > 0) ? s[b - 1] : 0;  // exclusive prefix
  int count = s[b] - my_base;

  // per-node histogram within bucket
  dcur[tid] = 0;
  __syncthreads();
  const unsigned* eb = &ebuf[b * BCAP];
  for (int e = tid; e < count; e += 256) {
    atomicAdd(&dcur[eb[e] >> 16], 1);
  }
  __syncthreads();
  int dn = dcur[tid];
  s[tid] = dn;
  for (int off = 1; off < 256; off <<= 1) {
    __syncthreads();
    int t = (tid >= off) ? s[tid - off] : 0;
    __syncthreads();
    s[tid] += t;
  }
  __syncthreads();
  doff[tid] = s[tid] - dn;  // exclusive within bucket
  int node = b * 256 + tid;
  if (node < NNODES) {
    deg[node] = dn;
    offs[node] = my_base + doff[tid];
  }
  dcur[tid] = 0;
  __syncthreads();

  // scatter src ids into CSR order (bucket-local ~8KB window)
  for (int e = tid; e < count; e += 256) {
    unsigned v = eb[e];
    int loc = v >> 16;
    int pos = my_base + doff[loc] + atomicAdd(&dcur[loc], 1);
    ssrc[pos] = (ushort)(v & 0xffffu);
  }
}

// ---------------- layer 1: mean-aggregate bf16 x -> bf16 agg ----------------
// 2 nodes per wave: 32 lanes per row, lane owns 4 channels (ushort4 = 8B load)
__global__ __launch_bounds__(256) void k_spmm1(
    const ushort* __restrict__ xh, const int* __restrict__ offs,
    const int* __restrict__ deg, const ushort* __restrict__ ssrc,
    ushort* __restrict__ aggh) {
  int wv = threadIdx.x >> 6;          // wave in block (0..3)
  int lane = threadIdx.x & 63;
  int half = lane >> 5;               // which node of the pair
  int l32 = lane & 31;                // 4-channel group
  int n = blockIdx.x * 8 + wv * 2 + half;
  if (n >= NNODES) return;
  int start = offs[n];
  int d = deg[n];
  float a0[4] = {0.f, 0.f, 0.f, 0.f};
  float a1[4] = {0.f, 0.f, 0.f, 0.f};
  float a2[4] = {0.f, 0.f, 0.f, 0.f};
  float a3[4] = {0.f, 0.f, 0.f, 0.f};
  int j = 0;
  for (; j + 3 < d; j += 4) {
    int s0 = ssrc[start + j + 0];
    int s1 = ssrc[start + j + 1];
    int s2 = ssrc[start + j + 2];
    int s3 = ssrc[start + j + 3];
    ushort4 u0 = *reinterpret_cast<const ushort4*>(&xh[s0 * FDIM + l32 * 4]);
    ushort4 u1 = *reinterpret_cast<const ushort4*>(&xh[s1 * FDIM + l32 * 4]);
    ushort4 u2 = *reinterpret_cast<const ushort4*>(&xh[s2 * FDIM + l32 * 4]);
    ushort4 u3 = *reinterpret_cast<const ushort4*>(&xh[s3 * FDIM + l32 * 4]);
    a0[0] += __uint_as_float((unsigned)u0.x << 16);
    a0[1] += __uint_as_float((unsigned)u0.y << 16);
    a0[2] += __uint_as_float((unsigned)u0.z << 16);
    a0[3] += __uint_as_float((unsigned)u0.w << 16);
    a1[0] += __uint_as_float((unsigned)u1.x << 16);
    a1[1] += __uint_as_float((unsigned)u1.y << 16);
    a1[2] += __uint_as_float((unsigned)u1.z << 16);
    a1[3] += __uint_as_float((unsigned)u1.w << 16);
    a2[0] += __uint_as_float((unsigned)u2.x << 16);
    a2[1] += __uint_as_float((unsigned)u2.y << 16);
    a2[2] += __uint_as_float((unsigned)u2.z << 16);
    a2[3] += __uint_as_float((unsigned)u2.w << 16);
    a3[0] += __uint_as_float((unsigned)u3.x << 16);
    a3[1] += __uint_as_float((unsigned)u3.y << 16);
    a3[2] += __uint_as_float((unsigned)u3.z << 16);
    a3[3] += __uint_as_float((unsigned)u3.w << 16);
  }
  for (; j < d; ++j) {
    int s0 = ssrc[start + j];
    ushort4 u0 = *reinterpret_cast<const ushort4*>(&xh[s0 * FDIM + l32 * 4]);
    a0[0] += __uint_as_float((unsigned)u0.x << 16);
    a0[1] += __uint_as_float((unsigned)u0.y << 16);
    a0[2] += __uint_as_float((unsigned)u0.z << 16);
    a0[3] += __uint_as_float((unsigned)u0.w << 16);
  }
  float inv = 1.0f / (float)(d > 0 ? d : 1);
  ushort4 o;
  o.x = f32_to_bf16_rne((a0[0] + a1[0] + a2[0] + a3[0]) * inv);
  o.y = f32_to_bf16_rne((a0[1] + a1[1] + a2[1] + a3[1]) * inv);
  o.z = f32_to_bf16_rne((a0[2] + a1[2] + a2[2] + a3[2]) * inv);
  o.w = f32_to_bf16_rne((a0[3] + a1[3] + a2[3] + a3[3]) * inv);
  *reinterpret_cast<ushort4*>(&aggh[(size_t)n * FDIM + l32 * 4]) = o;
}

// ---------------- fused dense: z = (relu(agg@W1+b1)*mask) @ W2 ----------------
// 256 thr = 4 waves; wave = 16 nodes; h-tile lives only in LDS (bf16).
// A-frag: lane holds A[m=lane&15][k=quad*8+j]; C/D: col=lane&15, row=quad*4+reg.
#define HT_STRIDE 132  // shorts; ds b16/b64 accesses are 2-way aliased (free)
__global__ __launch_bounds__(256) void k_dense(
    const ushort* __restrict__ aggh, const ushort* __restrict__ W1T,
    const float* __restrict__ b1, const float* __restrict__ mask,
    const ushort* __restrict__ W2T, ushort* __restrict__ zh) {
  __shared__ ushort hT[4][16 * HT_STRIDE];
  int w = threadIdx.x >> 6;
  int lane = threadIdx.x & 63;
  int nw = blockIdx.x * 64 + w * 16;
  if (nw >= NNODES) return;  // whole-wave tail (NNODES % 16 == 0)
  int l15 = lane & 15, quad = lane >> 4;

  f32x4 acc[8];
  #pragma unroll
  for (int ct = 0; ct < 8; ++ct) acc[ct] = (f32x4){0.f, 0.f, 0.f, 0.f};

  const ushort* arow = &aggh[(size_t)(nw + l15) * 128 + quad * 8];
  #pragma unroll
  for (int kk = 0; kk < 4; ++kk) {
    bf16x8 a = *reinterpret_cast<const bf16x8*>(arow + kk * 32);
    #pragma unroll
    for (int ct = 0; ct < 8; ++ct) {
      bf16x8 b = *reinterpret_cast<const bf16x8*>(
          &W1T[(size_t)(ct * 16 + l15) * 128 + kk * 32 + quad * 8]);
      acc[ct] = __builtin_amdgcn_mfma_f32_16x16x32_bf16(a, b, acc[ct], 0, 0, 0);
    }
  }

  // epilogue: +b1, relu, *mask -> bf16 LDS tile [row=node_local][col]
  ushort* ht = hT[w];
  #pragma unroll
  for (int ct = 0; ct < 8; ++ct) {
    int col = ct * 16 + l15;
    float bb = b1[col];
    #pragma unroll
    for (int r = 0; r < 4; ++r) {
      int node = nw + quad * 4 + r;
      float v = acc[ct][r] + bb;
      v = v > 0.f ? v : 0.f;
      v *= mask[(size_t)node * 128 + col];
      ht[(quad * 4 + r) * HT_STRIDE + col] = f32_to_bf16_rne(v);
    }
  }
  // wave-private tile: no __syncthreads needed (compiler inserts lgkmcnt)

  // second GEMM: z_tile[16n x 16c] = hT @ W2  (4 x K=32 MFMA steps)
  f32x4 zacc = (f32x4){0.f, 0.f, 0.f, 0.f};
  #pragma unroll
  for (int kk = 0; kk < 4; ++kk) {
    const ushort* ap = &ht[l15 * HT_STRIDE + kk * 32 + quad * 8];
    ushort4 alo = *reinterpret_cast<const ushort4*>(ap);      // 8B-aligned LDS reads
    ushort4 ahi = *reinterpret_cast<const ushort4*>(ap + 4);
    bf16x8 a2 = (bf16x8){(short)alo.x, (short)alo.y, (short)alo.z, (short)alo.w,
                         (short)ahi.x, (short)ahi.y, (short)ahi.z, (short)ahi.w};
    bf16x8 b2 = *reinterpret_cast<const bf16x8*>(&W2T[l15 * 128 + kk * 32 + quad * 8]);
    zacc = __builtin_amdgcn_mfma_f32_16x16x32_bf16(a2, b2, zacc, 0, 0, 0);
  }
  #pragma unroll
  for (int r = 0; r < 4; ++r) {
    zh[(size_t)(nw + quad * 4 + r) * 16 + l15] = f32_to_bf16_rne(zacc[r]);
  }
}

// ---------------- layer 2 aggregate + bias: out = mean(z) + b2 ----------------
// block = 128 threads = 8 nodes x 16 channels; z is bf16 (32B rows)
__global__ void k_spmm2(const ushort* __restrict__ zh, const int* __restrict__ offs,
                        const int* __restrict__ deg, const ushort* __restrict__ ssrc,
                        const float* __restrict__ b2, float* __restrict__ out) {
  int tid = threadIdx.x;
  int nl = tid >> 4, c = tid & 15;
  int n = blockIdx.x * 8 + nl;
  if (n >= NNODES) return;
  int start = offs[n], d = deg[n];
  float a0 = 0.f, a1 = 0.f, a2 = 0.f, a3 = 0.f;
  int j = 0;
  for (; j + 3 < d; j += 4) {
    int s0 = ssrc[start + j + 0], s1 = ssrc[start + j + 1];
    int s2 = ssrc[start + j + 2], s3 = ssrc[start + j + 3];
    a0 += __uint_as_float((unsigned)zh[s0 * 16 + c] << 16);
    a1 += __uint_as_float((unsigned)zh[s1 * 16 + c] << 16);
    a2 += __uint_as_float((unsigned)zh[s2 * 16 + c] << 16);
    a3 += __uint_as_float((unsigned)zh[s3 * 16 + c] << 16);
  }
  for (; j < d; ++j) a0 += __uint_as_float((unsigned)zh[ssrc[start + j] * 16 + c] << 16);
  out[n * 16 + c] = (a0 + a1 + a2 + a3) / (float)(d > 0 ? d : 1) + b2[c];
}

// ---------------- launch ----------------

extern "C" void kernel_launch(void* const* d_in, const int* in_sizes, int n_in,
                              void* d_out, int out_size, void* d_ws, size_t ws_size,
                              hipStream_t stream) {
  const float* x    = (const float*)d_in[0];
  const int*   ei   = (const int*)d_in[1];
  const float* W1   = (const float*)d_in[2];
  const float* b1   = (const float*)d_in[3];
  const float* W2   = (const float*)d_in[4];
  const float* b2   = (const float*)d_in[5];
  const float* mask = (const float*)d_in[6];
  float* out = (float*)d_out;

  const int* src = ei;            // edge_index[0]
  const int* dst = ei + NEDGES;   // edge_index[1]

  char* ws = (char*)d_ws;
  size_t o = 0;
  auto alloc = [&](size_t bytes) -> void* {
    void* p = ws + o;
    o += (bytes + 255) & ~(size_t)255;
    return p;
  };
  ushort*   aggh = (ushort*)alloc((size_t)NNODES * 128 * 2);
  ushort*   xh   = (ushort*)alloc((size_t)NNODES * 128 * 2);
  ushort*   zh   = (ushort*)alloc((size_t)NNODES * 16 * 2);
  ushort*   W1T  = (ushort*)alloc((size_t)128 * 128 * 2);
  ushort*   W2T  = (ushort*)alloc((size_t)16 * 128 * 2);
  int*      deg  = (int*)alloc((size_t)NNODES * 4);
  int*      offs = (int*)alloc((size_t)NNODES * 4);
  int*      gcur = (int*)alloc((size_t)NBUCK * 4);
  unsigned* ebuf = (unsigned*)alloc((size_t)NBUCK * BCAP * 4);
  ushort*   ssrc = (ushort*)alloc((size_t)NEDGES * 2);

  int prep_threads = 1600000 + 16384 + 2048 + NBUCK;

  k_prep<<<(prep_threads + 255) / 256, 256, 0, stream>>>(x, xh, W1, W1T, W2, W2T, gcur);
  k_binA<<<(NEDGES + 2047) / 2048, 256, 0, stream>>>(src, dst, gcur, ebuf);
  k_binB<<<NBUCK, 256, 0, stream>>>(gcur, ebuf, deg, offs, ssrc);
  k_spmm1<<<(NNODES + 7) / 8, 256, 0, stream>>>(xh, offs, deg, ssrc, aggh);
  k_dense<<<(NNODES + 63) / 64, 256, 0, stream>>>(aggh, W1T, b1, mask, W2T, zh);
  k_spmm2<<<(NNODES + 7) / 8, 128, 0, stream>>>(zh, offs, deg, ssrc, b2, out);
}

// Round 8
// 185.405 us; speedup vs baseline: 1.6676x; 1.0084x over previous
//
#include <hip/hip_runtime.h>

#define NNODES 50000
#define NEDGES 800000
#define FDIM 128
#define HDIM 128
#define CDIM 16

#define NBUCK 256
#define BCAP 6144  // per-bucket capacity: mean 4096, sd 64 -> 32 sigma headroom

typedef __attribute__((ext_vector_type(8))) short bf16x8;
typedef __attribute__((ext_vector_type(4))) float f32x4;

__device__ __forceinline__ ushort f32_to_bf16_rne(float f) {
  unsigned u = __float_as_uint(f);
  unsigned rounded = u + 0x7fffu + ((u >> 16) & 1u);
  return (ushort)(rounded >> 16);
}
__device__ __forceinline__ float bf_lo(unsigned u) { return __uint_as_float(u << 16); }
__device__ __forceinline__ float bf_hi(unsigned u) { return __uint_as_float(u & 0xffff0000u); }

// ---------------- prep: cast x->bf16 + W1T + W2T + init gcur ----------------
__global__ void k_prep(const float* __restrict__ x, ushort* __restrict__ xh,
                       const float* __restrict__ W1, ushort* __restrict__ W1T,
                       const float* __restrict__ W2, ushort* __restrict__ W2T,
                       int* __restrict__ gcur) {
  int t = blockIdx.x * blockDim.x + threadIdx.x;
  if (t < 1600000) {
    float4 v = *reinterpret_cast<const float4*>(&x[t * 4]);
    ushort4 o;
    o.x = f32_to_bf16_rne(v.x);
    o.y = f32_to_bf16_rne(v.y);
    o.z = f32_to_bf16_rne(v.z);
    o.w = f32_to_bf16_rne(v.w);
    *reinterpret_cast<ushort4*>(&xh[t * 4]) = o;
    return;
  }
  t -= 1600000;
  if (t < 16384) {  // W1T[c][k] = bf16(W1[k][c])
    int c = t >> 7, k = t & 127;
    W1T[c * 128 + k] = f32_to_bf16_rne(W1[k * 128 + c]);
    return;
  }
  t -= 16384;
  if (t < 2048) {  // W2T[c][k] = bf16(W2[k][c])
    int c = t >> 7, k = t & 127;
    W2T[c * 128 + k] = f32_to_bf16_rne(W2[k * 16 + c]);
    return;
  }
  t -= 2048;
  if (t < NBUCK) gcur[t] = t * BCAP;
}

// ---------------- phase A: bucket edges by dst>>8 ----------------
__global__ __launch_bounds__(256) void k_binA(
    const int* __restrict__ src, const int* __restrict__ dst,
    int* __restrict__ gcur, unsigned* __restrict__ ebuf) {
  __shared__ int cnt[NBUCK];
  __shared__ int base[NBUCK];
  int tid = threadIdx.x;
  int e0 = blockIdx.x * 2048;
  cnt[tid] = 0;
  __syncthreads();
  int sv[8], dv[8];
  #pragma unroll
  for (int i = 0; i < 8; ++i) {
    int e = e0 + i * 256 + tid;
    if (e < NEDGES) {
      sv[i] = src[e];
      dv[i] = dst[e];
      atomicAdd(&cnt[dv[i] >> 8], 1);
    } else {
      dv[i] = -1;
    }
  }
  __syncthreads();
  base[tid] = atomicAdd(&gcur[tid], cnt[tid]);
  cnt[tid] = 0;  // reuse as local cursor
  __syncthreads();
  #pragma unroll
  for (int i = 0; i < 8; ++i) {
    if (dv[i] >= 0) {
      int b = dv[i] >> 8;
      int pos = base[b] + atomicAdd(&cnt[b], 1);
      if (pos < (b + 1) * BCAP)  // safety clamp (statistically impossible)
        ebuf[pos] = ((unsigned)(dv[i] & 255) << 16) | (unsigned)sv[i];
    }
  }
}

// ---------------- phase B: per-bucket CSR finalize (all atomics in LDS) -----
__global__ __launch_bounds__(256) void k_binB(
    const int* __restrict__ gcur, const unsigned* __restrict__ ebuf,
    int* __restrict__ deg, int* __restrict__ offs, ushort* __restrict__ ssrc) {
  __shared__ int s[NBUCK];
  __shared__ int doff[NBUCK];
  __shared__ int dcur[NBUCK];
  int tid = threadIdx.x;
  int b = blockIdx.x;

  int c = gcur[tid] - tid * BCAP;
  if (c > BCAP) c = BCAP;
  s[tid] = c;
  for (int off = 1; off < 256; off <<= 1) {
    __syncthreads();
    int t = (tid >= off) ? s[tid - off] : 0;
    __syncthreads();
    s[tid] += t;
  }
  __syncthreads();
  int my_base = (b > 0) ? s[b - 1] : 0;  // exclusive prefix
  int count = s[b] - my_base;

  dcur[tid] = 0;
  __syncthreads();
  const unsigned* eb = &ebuf[b * BCAP];
  for (int e = tid; e < count; e += 256) {
    atomicAdd(&dcur[eb[e] >> 16], 1);
  }
  __syncthreads();
  int dn = dcur[tid];
  s[tid] = dn;
  for (int off = 1; off < 256; off <<= 1) {
    __syncthreads();
    int t = (tid >= off) ? s[tid - off] : 0;
    __syncthreads();
    s[tid] += t;
  }
  __syncthreads();
  doff[tid] = s[tid] - dn;  // exclusive within bucket
  int node = b * 256 + tid;
  if (node < NNODES) {
    deg[node] = dn;
    offs[node] = my_base + doff[tid];
  }
  dcur[tid] = 0;
  __syncthreads();

  for (int e = tid; e < count; e += 256) {
    unsigned v = eb[e];
    int loc = v >> 16;
    int pos = my_base + doff[loc] + atomicAdd(&dcur[loc], 1);
    ssrc[pos] = (ushort)(v & 0xffffu);
  }
}

// ---------------- layer 1: mean-aggregate bf16 x -> bf16 agg ----------------
// 16 node-groups per block; node-group = 16 lanes, lane owns 8 channels (uint4
// = 16B load -> one 1KiB coalesced fetch per wave per instr). 4 edge streams.
__global__ __launch_bounds__(256) void k_spmm1(
    const ushort* __restrict__ xh, const int* __restrict__ offs,
    const int* __restrict__ deg, const ushort* __restrict__ ssrc,
    ushort* __restrict__ aggh) {
  int tid = threadIdx.x;
  int grp = tid >> 4;   // node within block (0..15)
  int l16 = tid & 15;   // channel group: ch [8*l16, 8*l16+8)
  int n = blockIdx.x * 16 + grp;
  if (n >= NNODES) return;
  int start = offs[n];
  int d = deg[n];
  const ushort* base = xh + l16 * 8;
  float a0[8] = {0,0,0,0,0,0,0,0};
  float a1[8] = {0,0,0,0,0,0,0,0};
  float a2[8] = {0,0,0,0,0,0,0,0};
  float a3[8] = {0,0,0,0,0,0,0,0};
  int j = 0;
  for (; j + 3 < d; j += 4) {
    int s0 = ssrc[start + j + 0];
    int s1 = ssrc[start + j + 1];
    int s2 = ssrc[start + j + 2];
    int s3 = ssrc[start + j + 3];
    uint4 u0 = *reinterpret_cast<const uint4*>(base + s0 * FDIM);
    uint4 u1 = *reinterpret_cast<const uint4*>(base + s1 * FDIM);
    uint4 u2 = *reinterpret_cast<const uint4*>(base + s2 * FDIM);
    uint4 u3 = *reinterpret_cast<const uint4*>(base + s3 * FDIM);
    a0[0] += bf_lo(u0.x); a0[1] += bf_hi(u0.x); a0[2] += bf_lo(u0.y); a0[3] += bf_hi(u0.y);
    a0[4] += bf_lo(u0.z); a0[5] += bf_hi(u0.z); a0[6] += bf_lo(u0.w); a0[7] += bf_hi(u0.w);
    a1[0] += bf_lo(u1.x); a1[1] += bf_hi(u1.x); a1[2] += bf_lo(u1.y); a1[3] += bf_hi(u1.y);
    a1[4] += bf_lo(u1.z); a1[5] += bf_hi(u1.z); a1[6] += bf_lo(u1.w); a1[7] += bf_hi(u1.w);
    a2[0] += bf_lo(u2.x); a2[1] += bf_hi(u2.x); a2[2] += bf_lo(u2.y); a2[3] += bf_hi(u2.y);
    a2[4] += bf_lo(u2.z); a2[5] += bf_hi(u2.z); a2[6] += bf_lo(u2.w); a2[7] += bf_hi(u2.w);
    a3[0] += bf_lo(u3.x); a3[1] += bf_hi(u3.x); a3[2] += bf_lo(u3.y); a3[3] += bf_hi(u3.y);
    a3[4] += bf_lo(u3.z); a3[5] += bf_hi(u3.z); a3[6] += bf_lo(u3.w); a3[7] += bf_hi(u3.w);
  }
  for (; j < d; ++j) {
    int s0 = ssrc[start + j];
    uint4 u0 = *reinterpret_cast<const uint4*>(base + s0 * FDIM);
    a0[0] += bf_lo(u0.x); a0[1] += bf_hi(u0.x); a0[2] += bf_lo(u0.y); a0[3] += bf_hi(u0.y);
    a0[4] += bf_lo(u0.z); a0[5] += bf_hi(u0.z); a0[6] += bf_lo(u0.w); a0[7] += bf_hi(u0.w);
  }
  float inv = 1.0f / (float)(d > 0 ? d : 1);
  unsigned r[4];
  #pragma unroll
  for (int k = 0; k < 4; ++k) {
    float e0 = (a0[2 * k] + a1[2 * k] + a2[2 * k] + a3[2 * k]) * inv;
    float e1 = (a0[2 * k + 1] + a1[2 * k + 1] + a2[2 * k + 1] + a3[2 * k + 1]) * inv;
    r[k] = (unsigned)f32_to_bf16_rne(e0) | ((unsigned)f32_to_bf16_rne(e1) << 16);
  }
  uint4 o; o.x = r[0]; o.y = r[1]; o.z = r[2]; o.w = r[3];
  *reinterpret_cast<uint4*>(&aggh[(size_t)n * FDIM + l16 * 8]) = o;
}

// ---------------- fused dense: z = (relu(agg@W1+b1)*mask) @ W2 ----------------
// 256 thr = 4 waves; wave = 16 nodes; h-tile lives only in LDS (bf16).
// A-frag: lane holds A[m=lane&15][k=quad*8+j]; C/D: col=lane&15, row=quad*4+reg.
#define HT_STRIDE 132  // shorts; ds b16/b64 accesses are 2-way aliased (free)
__global__ __launch_bounds__(256) void k_dense(
    const ushort* __restrict__ aggh, const ushort* __restrict__ W1T,
    const float* __restrict__ b1, const float* __restrict__ mask,
    const ushort* __restrict__ W2T, ushort* __restrict__ zh) {
  __shared__ ushort hT[4][16 * HT_STRIDE];
  int w = threadIdx.x >> 6;
  int lane = threadIdx.x & 63;
  int nw = blockIdx.x * 64 + w * 16;
  if (nw >= NNODES) return;  // whole-wave tail (NNODES % 16 == 0)
  int l15 = lane & 15, quad = lane >> 4;

  f32x4 acc[8];
  #pragma unroll
  for (int ct = 0; ct < 8; ++ct) acc[ct] = (f32x4){0.f, 0.f, 0.f, 0.f};

  const ushort* arow = &aggh[(size_t)(nw + l15) * 128 + quad * 8];
  #pragma unroll
  for (int kk = 0; kk < 4; ++kk) {
    bf16x8 a = *reinterpret_cast<const bf16x8*>(arow + kk * 32);
    #pragma unroll
    for (int ct = 0; ct < 8; ++ct) {
      bf16x8 b = *reinterpret_cast<const bf16x8*>(
          &W1T[(size_t)(ct * 16 + l15) * 128 + kk * 32 + quad * 8]);
      acc[ct] = __builtin_amdgcn_mfma_f32_16x16x32_bf16(a, b, acc[ct], 0, 0, 0);
    }
  }

  // epilogue: +b1, relu, *mask -> bf16 LDS tile [row=node_local][col]
  ushort* ht = hT[w];
  #pragma unroll
  for (int ct = 0; ct < 8; ++ct) {
    int col = ct * 16 + l15;
    float bb = b1[col];
    #pragma unroll
    for (int r = 0; r < 4; ++r) {
      int node = nw + quad * 4 + r;
      float v = acc[ct][r] + bb;
      v = v > 0.f ? v : 0.f;
      v *= mask[(size_t)node * 128 + col];
      ht[(quad * 4 + r) * HT_STRIDE + col] = f32_to_bf16_rne(v);
    }
  }
  // wave-private tile: no __syncthreads needed (compiler inserts lgkmcnt)

  // second GEMM: z_tile[16n x 16c] = hT @ W2  (4 x K=32 MFMA steps)
  f32x4 zacc = (f32x4){0.f, 0.f, 0.f, 0.f};
  #pragma unroll
  for (int kk = 0; kk < 4; ++kk) {
    const ushort* ap = &ht[l15 * HT_STRIDE + kk * 32 + quad * 8];
    ushort4 alo = *reinterpret_cast<const ushort4*>(ap);      // 8B-aligned LDS reads
    ushort4 ahi = *reinterpret_cast<const ushort4*>(ap + 4);
    bf16x8 a2 = (bf16x8){(short)alo.x, (short)alo.y, (short)alo.z, (short)alo.w,
                         (short)ahi.x, (short)ahi.y, (short)ahi.z, (short)ahi.w};
    bf16x8 b2 = *reinterpret_cast<const bf16x8*>(&W2T[l15 * 128 + kk * 32 + quad * 8]);
    zacc = __builtin_amdgcn_mfma_f32_16x16x32_bf16(a2, b2, zacc, 0, 0, 0);
  }
  #pragma unroll
  for (int r = 0; r < 4; ++r) {
    zh[(size_t)(nw + quad * 4 + r) * 16 + l15] = f32_to_bf16_rne(zacc[r]);
  }
}

// ---------------- layer 2 aggregate + bias: out = mean(z) + b2 ----------------
__global__ void k_spmm2(const ushort* __restrict__ zh, const int* __restrict__ offs,
                        const int* __restrict__ deg, const ushort* __restrict__ ssrc,
                        const float* __restrict__ b2, float* __restrict__ out) {
  int tid = threadIdx.x;
  int nl = tid >> 4, c = tid & 15;
  int n = blockIdx.x * 8 + nl;
  if (n >= NNODES) return;
  int start = offs[n], d = deg[n];
  float a0 = 0.f, a1 = 0.f, a2 = 0.f, a3 = 0.f;
  int j = 0;
  for (; j + 3 < d; j += 4) {
    int s0 = ssrc[start + j + 0], s1 = ssrc[start + j + 1];
    int s2 = ssrc[start + j + 2], s3 = ssrc[start + j + 3];
    a0 += __uint_as_float((unsigned)zh[s0 * 16 + c] << 16);
    a1 += __uint_as_float((unsigned)zh[s1 * 16 + c] << 16);
    a2 += __uint_as_float((unsigned)zh[s2 * 16 + c] << 16);
    a3 += __uint_as_float((unsigned)zh[s3 * 16 + c] << 16);
  }
  for (; j < d; ++j) a0 += __uint_as_float((unsigned)zh[ssrc[start + j] * 16 + c] << 16);
  out[n * 16 + c] = (a0 + a1 + a2 + a3) / (float)(d > 0 ? d : 1) + b2[c];
}

// ---------------- launch ----------------

extern "C" void kernel_launch(void* const* d_in, const int* in_sizes, int n_in,
                              void* d_out, int out_size, void* d_ws, size_t ws_size,
                              hipStream_t stream) {
  const float* x    = (const float*)d_in[0];
  const int*   ei   = (const int*)d_in[1];
  const float* W1   = (const float*)d_in[2];
  const float* b1   = (const float*)d_in[3];
  const float* W2   = (const float*)d_in[4];
  const float* b2   = (const float*)d_in[5];
  const float* mask = (const float*)d_in[6];
  float* out = (float*)d_out;

  const int* src = ei;            // edge_index[0]
  const int* dst = ei + NEDGES;   // edge_index[1]

  char* ws = (char*)d_ws;
  size_t o = 0;
  auto alloc = [&](size_t bytes) -> void* {
    void* p = ws + o;
    o += (bytes + 255) & ~(size_t)255;
    return p;
  };
  ushort*   aggh = (ushort*)alloc((size_t)NNODES * 128 * 2);
  ushort*   xh   = (ushort*)alloc((size_t)NNODES * 128 * 2);
  ushort*   zh   = (ushort*)alloc((size_t)NNODES * 16 * 2);
  ushort*   W1T  = (ushort*)alloc((size_t)128 * 128 * 2);
  ushort*   W2T  = (ushort*)alloc((size_t)16 * 128 * 2);
  int*      deg  = (int*)alloc((size_t)NNODES * 4);
  int*      offs = (int*)alloc((size_t)NNODES * 4);
  int*      gcur = (int*)alloc((size_t)NBUCK * 4);
  unsigned* ebuf = (unsigned*)alloc((size_t)NBUCK * BCAP * 4);
  ushort*   ssrc = (ushort*)alloc((size_t)NEDGES * 2);

  int prep_threads = 1600000 + 16384 + 2048 + NBUCK;

  k_prep<<<(prep_threads + 255) / 256, 256, 0, stream>>>(x, xh, W1, W1T, W2, W2T, gcur);
  k_binA<<<(NEDGES + 2047) / 2048, 256, 0, stream>>>(src, dst, gcur, ebuf);
  k_binB<<<NBUCK, 256, 0, stream>>>(gcur, ebuf, deg, offs, ssrc);
  k_spmm1<<<(NNODES + 15) / 16, 256, 0, stream>>>(xh, offs, deg, ssrc, aggh);
  k_dense<<<(NNODES + 63) / 64, 256, 0, stream>>>(aggh, W1T, b1, mask, W2T, zh);
  k_spmm2<<<(NNODES + 7) / 8, 128, 0, stream>>>(zh, offs, deg, ssrc, b2, out);
}